// Round 9
// baseline (403.183 us; speedup 1.0000x reference)
//
#include <hip/hip_runtime.h>
#include <stdint.h>

#define TB_ 32
#define C_ 256
#define N_ 3136
#define TBC (C_ * N_)            // 802816 elems per (t,b) per 256-ch tensor
#define ACT_SZ (TB_ * TBC)       // 25690112
#define XSB_TB 819200            // elems per tb in blocked layouts (200 groups * 4096)
#define PARTS 7
#define CHUNK 448                // 3136/7, multiple of 16

typedef __attribute__((ext_vector_type(8))) short bf16x8;
typedef __attribute__((ext_vector_type(4))) float f32x4;

__device__ __forceinline__ void glds16(const void* gp, void* lp) {
  __builtin_amdgcn_global_load_lds(
      (const __attribute__((address_space(1))) unsigned int*)gp,
      (__attribute__((address_space(3))) unsigned int*)lp, 16, 0, 0);
}

__device__ __forceinline__ unsigned short bf16rn(float f, float* val) {
  unsigned b = __float_as_uint(f);
  unsigned r = (b + 0x7fffu + ((b >> 16) & 1u)) >> 16;
  *val = __uint_as_float(r << 16);
  return (unsigned short)r;
}

__device__ __forceinline__ int dot4u(unsigned a, unsigned b, int c) {
  c += (int)(a & 255u)         * (int)(b & 255u);
  c += (int)((a >> 8) & 255u)  * (int)((b >> 8) & 255u);
  c += (int)((a >> 16) & 255u) * (int)((b >> 16) & 255u);
  c += (int)(a >> 24)          * (int)(b >> 24);
  return c;
}

__device__ __forceinline__ int dot4(unsigned a, unsigned b, int c) {
#if defined(__has_builtin)
#if __has_builtin(__builtin_amdgcn_sdot4)
  return __builtin_amdgcn_sdot4((int)a, (int)b, c, false);
#else
  return dot4u(a, b, c);
#endif
#else
  return dot4u(a, b, c);
#endif
}

// ---------------------------------------------------------------------------
// K0: fused prep — bx 0: BN fold; 1..1024: weight split; 1025..1056: kvg zero
// ---------------------------------------------------------------------------
__global__ __launch_bounds__(256) void prep_all(
    const float* __restrict__ qbn, const float* __restrict__ kbn,
    const float* __restrict__ vbn, const float* __restrict__ pbn,
    const float* __restrict__ qw, const float* __restrict__ kw,
    const float* __restrict__ vw, const float* __restrict__ pw,
    float* __restrict__ bnw, unsigned short* __restrict__ wsp,
    int* __restrict__ kvg) {
  const int bx = blockIdx.x;
  const int t = threadIdx.x;
  if (bx == 0) {
    const float* ps[4] = {qbn, kbn, vbn, pbn};
#pragma unroll
    for (int i = 0; i < 4; ++i) {
      const float* p = ps[i];
      float g = p[t], be = p[256 + t], mn = p[512 + t], vr = p[768 + t];
      float s = g / sqrtf(vr + 1e-5f);
      float b = __fsub_rn(be, __fmul_rn(mn, s));
      bnw[i * 512 + t] = s;
      bnw[i * 512 + 256 + t] = b;
    }
  } else if (bx <= 1024) {
    const float* Ws[4] = {qw, kw, vw, pw};
    int id = bx - 1, co = id & 255, m = id >> 8;
    float w = Ws[m][co * 256 + t];
    float h1, h2, h3r;
    unsigned short u1 = bf16rn(w, &h1);
    float r1 = __fsub_rn(w, h1);
    unsigned short u2 = bf16rn(r1, &h2);
    float r2 = __fsub_rn(r1, h2);
    unsigned short u3 = bf16rn(r2, &h3r);   // exact: r2 has <=8 significant bits
    int rt = co >> 7, ks = t >> 5;
    int lane = (co & 15) + 16 * ((t >> 3) & 3);
    unsigned short us[3] = {u1, u2, u3};
#pragma unroll
    for (int sp = 0; sp < 3; ++sp) {
      size_t off = (size_t)((((m * 3 + sp) * 2 + rt) * 8 + ks)) * 4096 + lane * 8 + (t & 7);
      wsp[off] = us[sp];
    }
  } else {
    int tb = bx - 1025;
    int4* p = (int4*)(kvg + (size_t)tb * 8192);
    for (int i = t; i < 2048; i += 256) p[i] = make_int4(0, 0, 0, 0);
  }
}

// ---------------------------------------------------------------------------
// K1: x -> spikes (bf16, exact 0..8) in blocked B-fragment layout (float4 loads)
// ---------------------------------------------------------------------------
__global__ __launch_bounds__(256) void quant_x_t(const float* __restrict__ x,
                                                 unsigned short* __restrict__ xsb) {
  __shared__ unsigned short s[64 * 68];
  const int t = threadIdx.x;
  const int n0 = blockIdx.x * 64;
  const int tb = blockIdx.y;
  const float* X = x + (size_t)tb * TBC;
  const int nl = t & 63, cq = t >> 6;
  const int c16 = t >> 4, p4 = (t & 15) * 4;

  unsigned short* dstb = xsb + (size_t)tb * XSB_TB;
  for (int cb = 0; cb < 4; ++cb) {
    int cbase = cb * 64;
#pragma unroll
    for (int i = 0; i < 4; ++i) {
      int c = i * 16 + c16;
      float4 v = *(const float4*)&X[(size_t)(cbase + c) * N_ + n0 + p4];
      unsigned short r0 = (unsigned short)(__float_as_uint(fminf(fmaxf(rintf(v.x), 0.f), 8.f)) >> 16);
      unsigned short r1 = (unsigned short)(__float_as_uint(fminf(fmaxf(rintf(v.y), 0.f), 8.f)) >> 16);
      unsigned short r2 = (unsigned short)(__float_as_uint(fminf(fmaxf(rintf(v.z), 0.f), 8.f)) >> 16);
      unsigned short r3 = (unsigned short)(__float_as_uint(fminf(fmaxf(rintf(v.w), 0.f), 8.f)) >> 16);
      uint2 pk2;
      pk2.x = (unsigned)r0 | ((unsigned)r1 << 16);
      pk2.y = (unsigned)r2 | ((unsigned)r3 << 16);
      *(uint2*)&s[c * 68 + p4] = pk2;
    }
    __syncthreads();
#pragma unroll 2
    for (int j = 0; j < 2; ++j) {
      int ccl = j * 4 + cq;
      int cc = cb * 8 + ccl;
      unsigned short v8[8];
#pragma unroll
      for (int d = 0; d < 8; ++d) v8[d] = s[(ccl * 8 + d) * 68 + nl];
      int n = n0 + nl;
      uint4 pk;
      pk.x = (unsigned)v8[0] | ((unsigned)v8[1] << 16);
      pk.y = (unsigned)v8[2] | ((unsigned)v8[3] << 16);
      pk.z = (unsigned)v8[4] | ((unsigned)v8[5] << 16);
      pk.w = (unsigned)v8[6] | ((unsigned)v8[7] << 16);
      *(uint4*)&dstb[(size_t)(n >> 4) * 4096 + cc * 128 + (n & 15) * 8] = pk;
    }
    __syncthreads();
  }
}

// ---------------------------------------------------------------------------
// K2: fused q/k/v GEMM. Round-15: 128x160 output tile (acc[4][5]) — modest
// N-widening within the VGPR budget (est ~115-125, stays 4-waves/SIMD class;
// round-7's acc[4][8] blew the unified file). LDS = 2 slots x (8KB A + 10KB
// B) = 36KB -> 4 blocks/CU (up from 3). LDS traffic/output -10%, barriers
// /output -20%. Schedule = proven round-12 2-slot form: {vmcnt(0); barrier;
// issue stage(st+1) into slot (st+1)&1; compute slot st&1} — slot (st+1)&1
// was read at st-1 (pre-barrier) -> race-free; one full step of latency
// cover. 20 n-tiles of 160 (3200>=3136): B group reads stay within the
// 200-group padded xsb (no OOB); tail guarded by n<N_ (garbage B cols only
// affect discarded outputs). Per-acc (sp,ks) MFMA chain unchanged ->
// bitwise-identical. grid 3840 = 80 octs x 48 (bijective XCD swizzle).
// ---------------------------------------------------------------------------
__global__ __launch_bounds__(256) void qkv_mfma_sw(
    const unsigned short* __restrict__ xsb, const unsigned short* __restrict__ wsp,
    const float* __restrict__ bnw,
    uint8_t* __restrict__ qsb, uint8_t* __restrict__ ks_, uint8_t* __restrict__ vs) {
  __shared__ __align__(16) char smem[36864];   // 2 slots x (8KB A + 10KB B)
  const int t = threadIdx.x;
  const int L = t & 63, w = t >> 6;
  const int wrow = w >> 1, wcol = w & 1;
  const int b = blockIdx.x;
  const int oct = b / 48, rem = b % 48;
  const int s = rem >> 3, gl = rem & 7;
  const int g = oct * 8 + gl;               // 0..639
  const int ntile = g % 20, tb = g / 20;
  const int conv = s >> 1, rt = s & 1;
  const int n0 = ntile * 160;

  // B base: 10 groups of 8192B per 160-tile
  const char* Bb = (const char*)(xsb + (size_t)tb * XSB_TB) + (size_t)ntile * 81920;
  const char* Ab = (const char*)wsp + ((size_t)(conv * 3) * 16 + rt * 8) * 8192;

  f32x4 acc[4][5];
#pragma unroll
  for (int i = 0; i < 4; ++i)
#pragma unroll
    for (int j = 0; j < 5; ++j) acc[i][j] = (f32x4){0.f, 0.f, 0.f, 0.f};

  // prologue: stage step 0 into slot 0
  {
    glds16(Ab + t * 16, smem + t * 16);
    glds16(Ab + t * 16 + 4096, smem + t * 16 + 4096);
    glds16(Bb + (size_t)w * 8192 + L * 16, smem + 8192 + t * 16);
    glds16(Bb + (size_t)(w + 4) * 8192 + L * 16, smem + 8192 + 4096 + t * 16);
    if (w < 2) glds16(Bb + (size_t)(w + 8) * 8192 + L * 16, smem + 8192 + 8192 + t * 16);
  }

  // step st: sp = st>>3, ks = st&7  (24 steps, 256x160 per block total M=256
  // via rt split: this block does rows rt*128..rt*128+127)
#pragma unroll 1
  for (int st = 0; st < 24; ++st) {
    asm volatile("s_waitcnt vmcnt(0)" ::: "memory");
    __builtin_amdgcn_s_barrier();
    const int s1 = st + 1;
    if (s1 < 24) {
      char* slotn = smem + (s1 & 1) * 18432;
      const char* Ak = Ab + (size_t)(((s1 >> 3) * 16) + (s1 & 7)) * 8192;
      glds16(Ak + t * 16, slotn + t * 16);
      glds16(Ak + t * 16 + 4096, slotn + t * 16 + 4096);
      const char* Bk = Bb + (size_t)(s1 & 7) * 1024;
      glds16(Bk + (size_t)w * 8192 + L * 16, slotn + 8192 + t * 16);
      glds16(Bk + (size_t)(w + 4) * 8192 + L * 16, slotn + 8192 + 4096 + t * 16);
      if (w < 2) glds16(Bk + (size_t)(w + 8) * 8192 + L * 16, slotn + 8192 + 8192 + t * 16);
    }
    char* slotc = smem + (st & 1) * 18432;
    bf16x8 af[4];
#pragma unroll
    for (int i = 0; i < 4; ++i)
      af[i] = *(const bf16x8*)(slotc + (wrow * 4 + i) * 1024 + L * 16);
#pragma unroll
    for (int j = 0; j < 5; ++j) {
      bf16x8 bfr = *(const bf16x8*)(slotc + 8192 + (wcol * 5 + j) * 1024 + L * 16);
#pragma unroll
      for (int i = 0; i < 4; ++i)
        acc[i][j] = __builtin_amdgcn_mfma_f32_16x16x32_bf16(af[i], bfr, acc[i][j], 0, 0, 0);
    }
  }

  const float* sbn = bnw + conv * 512;
  const int rbase = rt * 128;
  if (conv == 0) {
    uint8_t* qtb = qsb + (size_t)tb * XSB_TB;   // u8 blocked, same group layout
#pragma unroll
    for (int i = 0; i < 4; ++i) {
      int co0 = rbase + wrow * 64 + i * 16 + ((L >> 4) << 2);
      float s0 = sbn[co0], b0 = sbn[256 + co0];
      float s1 = sbn[co0 + 1], b1 = sbn[256 + co0 + 1];
      float s2v = sbn[co0 + 2], b2 = sbn[256 + co0 + 2];
      float s3 = sbn[co0 + 3], b3 = sbn[256 + co0 + 3];
#pragma unroll
      for (int j = 0; j < 5; ++j) {
        int n = n0 + wcol * 80 + j * 16 + (L & 15);
        if (n < N_) {
          float ss[4] = {s0, s1, s2v, s3}, bb[4] = {b0, b1, b2, b3};
          unsigned wb = 0;
#pragma unroll
          for (int r = 0; r < 4; ++r) {
            float y = acc[i][j][r] * 0.125f;
            float tt = __fadd_rn(__fmul_rn(y, ss[r]), bb[r]);
            float rr = fminf(fmaxf(rintf(tt), 0.f), 8.f);
            wb |= ((unsigned)(uint8_t)rr) << (8 * r);
          }
          *(unsigned*)&qtb[(size_t)(n >> 4) * 4096 + (co0 >> 3) * 128 + (n & 15) * 8 + (co0 & 7)] = wb;
        }
      }
    }
  } else {
    uint8_t* outp = (conv == 1 ? ks_ : vs) + (size_t)tb * TBC;
#pragma unroll
    for (int i = 0; i < 4; ++i) {
      int co0 = rbase + wrow * 64 + i * 16 + ((L >> 4) << 2);
#pragma unroll
      for (int j = 0; j < 5; ++j) {
        int n = n0 + wcol * 80 + j * 16 + (L & 15);
        if (n < N_) {
#pragma unroll
          for (int r = 0; r < 4; ++r) {
            int co = co0 + r;
            float y = acc[i][j][r] * 0.125f;
            float tt = __fadd_rn(__fmul_rn(y, sbn[co]), sbn[256 + co]);
            float rr = fminf(fmaxf(rintf(tt), 0.f), 8.f);
            outp[(size_t)co * N_ + n] = (uint8_t)rr;
          }
        }
      }
    }
  }
}

// ---------------------------------------------------------------------------
// K3: partial kv = k^T v, exact i32 atomics. sv XOR swizzle (round-7,
// verified): v-read conflict 4-way -> 2-way. grid (8,32,PARTS)
// ---------------------------------------------------------------------------
__global__ __launch_bounds__(256) void attn_kv(
    const uint8_t* __restrict__ ks, const uint8_t* __restrict__ vs,
    int* __restrict__ kvg) {
  const int h = blockIdx.x, tb = blockIdx.y, part = blockIdx.z;
  const int tid = threadIdx.x;
  __shared__ unsigned sk[32][68];
  __shared__ unsigned sv[32][68];
  const uint8_t* K = ks + (size_t)tb * TBC + h * 32 * N_;
  const uint8_t* V = vs + (size_t)tb * TBC + h * 32 * N_;
  const int d0 = (tid >> 4) * 2;
  const int e0 = (tid & 15) * 2;
  const int vsw = ((e0 >> 1) & 7) << 2;   // read-side XOR for rows e0, e0+1
  const int pbase = part * CHUNK;
  const int pend = pbase + CHUNK;
  int acc[2][2] = {};

  for (int nt = 0; nt < 2; ++nt) {
    int n0 = pbase + nt * 256;
    if (n0 >= pend) break;
    if (nt) __syncthreads();
#pragma unroll
    for (int i = 0; i < 8; ++i) {
      int idx = tid + i * 256;
      int d = idx >> 6, w2 = idx & 63;
      int n = n0 + w2 * 4;
      unsigned kw_ = 0, vw_ = 0;
      if (n < pend) {
        kw_ = *(const unsigned*)&K[d * N_ + n];
        vw_ = *(const unsigned*)&V[d * N_ + n];
      }
      sk[d][w2] = kw_;
      sv[d][w2 ^ (((d >> 1) & 7) << 2)] = vw_;
    }
    __syncthreads();
#pragma unroll
    for (int w2 = 0; w2 < 64; w2 += 4) {
      uint4 ka = *(const uint4*)&sk[d0][w2];
      uint4 kb = *(const uint4*)&sk[d0 + 1][w2];
      uint4 va = *(const uint4*)&sv[e0][w2 ^ vsw];
      uint4 vb = *(const uint4*)&sv[e0 + 1][w2 ^ vsw];
      unsigned kwds[2][4] = {{ka.x, ka.y, ka.z, ka.w}, {kb.x, kb.y, kb.z, kb.w}};
      unsigned vwds[2][4] = {{va.x, va.y, va.z, va.w}, {vb.x, vb.y, vb.z, vb.w}};
#pragma unroll
      for (int di = 0; di < 2; ++di)
#pragma unroll
        for (int ej = 0; ej < 2; ++ej)
#pragma unroll
          for (int c = 0; c < 4; ++c)
            acc[di][ej] = dot4(kwds[di][c], vwds[ej][c], acc[di][ej]);
    }
  }
  int* dst = kvg + ((size_t)(tb * 8 + h)) * 1024;
  atomicAdd(&dst[d0 * 32 + e0], acc[0][0]);
  atomicAdd(&dst[d0 * 32 + e0 + 1], acc[0][1]);
  atomicAdd(&dst[(d0 + 1) * 32 + e0], acc[1][0]);
  atomicAdd(&dst[(d0 + 1) * 32 + e0 + 1], acc[1][1]);
}

// ---------------------------------------------------------------------------
// K3b: split kv ints (< 2^18, nonneg) into 3 truncation-exact bf16 parts,
// laid out as MFMA A-fragment images. Round-15: widened 32 -> 256 blocks
// (was using 32 of 256 CUs; pure tail-latency kernel).
// ---------------------------------------------------------------------------
__global__ __launch_bounds__(256) void kv_finish(const int* __restrict__ kvg,
                                                 unsigned short* __restrict__ kvimg) {
  const int bx = blockIdx.x, t = threadIdx.x;
  const int tb = bx >> 3;
  const int base = (bx & 7) * 1024;
  const int* src = kvg + (size_t)tb * 8192;
  unsigned short* dst = kvimg + (size_t)tb * 24576;
#pragma unroll
  for (int i = 0; i < 4; ++i) {
    int idx = base + t + i * 256;
    int h = idx >> 10, rem = idx & 1023, d = rem >> 5, e = rem & 31;
    int v = src[idx];
    int b1 = (v > 0) ? (32 - __clz(v)) : 0;
    int sh1 = b1 > 8 ? b1 - 8 : 0;
    int hi = (v >> sh1) << sh1;
    int r1 = v - hi;
    int b2 = (r1 > 0) ? (32 - __clz(r1)) : 0;
    int sh2 = b2 > 8 ? b2 - 8 : 0;
    int mid = (r1 >> sh2) << sh2;
    int r2 = r1 - mid;
    int parts[3] = {hi, mid, r2};
    int mtile = e >> 4, lane = (e & 15) + 16 * (d >> 3), j = d & 7;
#pragma unroll
    for (int sp = 0; sp < 3; ++sp) {
      float f = (float)parts[sp];   // exact: <=8 significant bits
      dst[(size_t)h * 3072 + (sp * 2 + mtile) * 512 + lane * 8 + j] =
          (unsigned short)(__float_as_uint(f) >> 16);
    }
  }
}

// ---------------------------------------------------------------------------
// K3c: o = quant(q . kv * scale) via bf16 MFMA. Round-14 form (double-
// buffered head pipeline, 1 barrier/head, T14 issue-early/write-late).
// ---------------------------------------------------------------------------
__global__ __launch_bounds__(256) void attn_o_mfma(
    const uint8_t* __restrict__ qsb, const unsigned short* __restrict__ kvimg,
    unsigned short* __restrict__ osb) {
  __shared__ __align__(16) char smem[28672];   // 2 x (8KB B-image + 6KB A-images)
  const int t = threadIdx.x;
  const int L = t & 63, wv = t >> 6;
  const int b = blockIdx.x;
  const int ntile = b % 25, tb = b / 25;
  const uint8_t* Q = qsb + (size_t)tb * XSB_TB + (size_t)ntile * 8 * 4096;
  const unsigned short* KV = kvimg + (size_t)tb * 24576;
  unsigned short* osb_tb = osb + (size_t)tb * XSB_TB;
  const float cscale = (float)(0.3535533905932738 / 512.0);

  // stage(0) fully (loads + writes) into buffer 0
  {
    char* smB = smem;
    char* smA = smem + 8192;
    const char* Ah = (const char*)KV;
    glds16(Ah + t * 16, smA + t * 16);
    if (t < 128) glds16(Ah + 4096 + t * 16, smA + 4096 + t * 16);
#pragma unroll
    for (int it = 0; it < 4; ++it) {
      int w2 = t + it * 256;
      int gl2 = w2 >> 7, wl = w2 & 127, ccp = wl >> 5;
      int rem = (w2 * 4) & 127, n16 = rem >> 3, k7b = rem & 7;
      unsigned wd = *(const unsigned*)&Q[(size_t)gl2 * 4096 + (0 * 4 + ccp) * 128 + n16 * 8 + k7b];
      unsigned short* ds = (unsigned short*)smB + gl2 * 512 + (ccp * 16 + n16) * 8 + k7b;
      float f0 = (float)(wd & 255u), f1 = (float)((wd >> 8) & 255u);
      float f2 = (float)((wd >> 16) & 255u), f3 = (float)(wd >> 24);
      uint2 pk;
      pk.x = (__float_as_uint(f0) >> 16) | ((__float_as_uint(f1) >> 16) << 16);
      pk.y = (__float_as_uint(f2) >> 16) | ((__float_as_uint(f3) >> 16) << 16);
      *(uint2*)ds = pk;
    }
  }

#pragma unroll 1
  for (int h = 0; h < 8; ++h) {
    __syncthreads();   // drains stage(h) glds16 + ds_writes; guards buffer reuse
    char* cur = smem + (h & 1) * 14336;
    char* smB = cur;
    char* smA = cur + 8192;
    // read B frags of head h
    bf16x8 bfr[2];
#pragma unroll
    for (int jj = 0; jj < 2; ++jj)
      bfr[jj] = *(const bf16x8*)(smB + (wv * 2 + jj) * 1024 + L * 16);
    // T14 issue-early: A-images(h+1) via glds16; Q words(h+1) into regs
    unsigned wd[4];
    if (h < 7) {
      char* alt = smem + ((h + 1) & 1) * 14336;
      const char* Ah = (const char*)(KV + (size_t)(h + 1) * 3072);
      glds16(Ah + t * 16, alt + 8192 + t * 16);
      if (t < 128) glds16(Ah + 4096 + t * 16, alt + 8192 + 4096 + t * 16);
#pragma unroll
      for (int it = 0; it < 4; ++it) {
        int w2 = t + it * 256;
        int gl2 = w2 >> 7, wl = w2 & 127, ccp = wl >> 5;
        int rem = (w2 * 4) & 127, n16 = rem >> 3, k7b = rem & 7;
        wd[it] = *(const unsigned*)&Q[(size_t)gl2 * 4096 + ((h + 1) * 4 + ccp) * 128 + n16 * 8 + k7b];
      }
    }
    // MFMAs of head h
    f32x4 acc[2][2];
#pragma unroll
    for (int i = 0; i < 2; ++i)
#pragma unroll
      for (int jj = 0; jj < 2; ++jj) acc[i][jj] = (f32x4){0.f, 0.f, 0.f, 0.f};
#pragma unroll
    for (int sp = 0; sp < 3; ++sp) {
      bf16x8 a0 = *(const bf16x8*)(smA + (sp * 2 + 0) * 1024 + L * 16);
      bf16x8 a1 = *(const bf16x8*)(smA + (sp * 2 + 1) * 1024 + L * 16);
#pragma unroll
      for (int jj = 0; jj < 2; ++jj) {
        acc[0][jj] = __builtin_amdgcn_mfma_f32_16x16x32_bf16(a0, bfr[jj], acc[0][jj], 0, 0, 0);
        acc[1][jj] = __builtin_amdgcn_mfma_f32_16x16x32_bf16(a1, bfr[jj], acc[1][jj], 0, 0, 0);
      }
    }
    // T14 write-late: unpack Q(h+1) -> alt B-image
    if (h < 7) {
      char* alt = smem + ((h + 1) & 1) * 14336;
#pragma unroll
      for (int it = 0; it < 4; ++it) {
        int w2 = t + it * 256;
        int gl2 = w2 >> 7, wl = w2 & 127, ccp = wl >> 5;
        int rem = (w2 * 4) & 127, n16 = rem >> 3, k7b = rem & 7;
        unsigned short* ds = (unsigned short*)alt + gl2 * 512 + (ccp * 16 + n16) * 8 + k7b;
        float f0 = (float)(wd[it] & 255u), f1 = (float)((wd[it] >> 8) & 255u);
        float f2 = (float)((wd[it] >> 16) & 255u), f3 = (float)(wd[it] >> 24);
        uint2 pk;
        pk.x = (__float_as_uint(f0) >> 16) | ((__float_as_uint(f1) >> 16) << 16);
        pk.y = (__float_as_uint(f2) >> 16) | ((__float_as_uint(f3) >> 16) << 16);
        *(uint2*)ds = pk;
      }
    }
    // epilogue of head h
#pragma unroll
    for (int i = 0; i < 2; ++i) {
      int c0 = h * 32 + i * 16 + ((L >> 4) << 2);
#pragma unroll
      for (int jj = 0; jj < 2; ++jj) {
        int n = ntile * 128 + (wv * 2 + jj) * 16 + (L & 15);
        if (n < N_) {
          unsigned short u[4];
#pragma unroll
          for (int r = 0; r < 4; ++r) {
            float of = acc[i][jj][r] * cscale;
            float rr = fminf(fmaxf(rintf(of), 0.f), 8.f);
            u[r] = (unsigned short)(__float_as_uint(rr) >> 16);
          }
          uint2 pk;
          pk.x = (unsigned)u[0] | ((unsigned)u[1] << 16);
          pk.y = (unsigned)u[2] | ((unsigned)u[3] << 16);
          *(uint2*)&osb_tb[(size_t)(n >> 4) * 4096 + (c0 >> 3) * 128 + (n & 15) * 8 + (c0 & 7)] = pk;
        }
      }
    }
  }
}

// ---------------------------------------------------------------------------
// K4: out = BN(pw @ os/8) via bf16 MFMA, 2 splits. Round-6 measured form
// (distance-2, 3-slot ring, 16 steps) — unchanged.
// ---------------------------------------------------------------------------
__global__ __launch_bounds__(256) void out_mfma_sw(
    const unsigned short* __restrict__ osb, const unsigned short* __restrict__ wsp,
    const float* __restrict__ bnw, float* __restrict__ out) {
  __shared__ __align__(16) char smem[49152];   // ring: 3 x (8KB A + 8KB B)
  const int t = threadIdx.x;
  const int L = t & 63, w = t >> 6;
  const int wrow = w >> 1, wcol = w & 1;
  const int b = blockIdx.x;
  const int oct = b / 16, rem = b % 16;
  const int rt = rem >> 3, gl = rem & 7;
  const int g = oct * 8 + gl;
  const int ntile = g % 25, tb = g / 25;
  const int n0 = ntile * 128;
  const char* Bb = (const char*)(osb + (size_t)tb * XSB_TB) + (size_t)ntile * 65536;
  const char* Ab = (const char*)wsp + ((size_t)9 * 16 + rt * 8) * 8192;

  f32x4 acc[4][4];
#pragma unroll
  for (int i = 0; i < 4; ++i)
#pragma unroll
    for (int j = 0; j < 4; ++j) acc[i][j] = (f32x4){0.f, 0.f, 0.f, 0.f};

  // prologue: stage step 0 -> slot 0, step 1 -> slot 1
  glds16(Ab + t * 16, smem + t * 16);
  glds16(Ab + t * 16 + 4096, smem + t * 16 + 4096);
  glds16(Bb + (size_t)w * 8192 + L * 16, smem + 8192 + t * 16);
  glds16(Bb + (size_t)(w + 4) * 8192 + L * 16, smem + 8192 + t * 16 + 4096);
  {
    char* slot1 = smem + 16384;
    const char* Ak1 = Ab + 8192;          // (sp=0, ks=1)
    glds16(Ak1 + t * 16, slot1 + t * 16);
    glds16(Ak1 + t * 16 + 4096, slot1 + t * 16 + 4096);
    const char* Bk1 = Bb + 1024;
    glds16(Bk1 + (size_t)w * 8192 + L * 16, slot1 + 8192 + t * 16);
    glds16(Bk1 + (size_t)(w + 4) * 8192 + L * 16, slot1 + 8192 + t * 16 + 4096);
  }

  // step st: sp = st>>3, ks = st&7  (16 steps)
#pragma unroll 1
  for (int st = 0; st < 16; ++st) {
    if (st < 15) {
      asm volatile("s_waitcnt vmcnt(4)" ::: "memory");
    } else {
      asm volatile("s_waitcnt vmcnt(0)" ::: "memory");
    }
    __builtin_amdgcn_s_barrier();
    const int s2 = st + 2;
    if (s2 < 16) {
      char* slotn = smem + (s2 % 3) * 16384;
      const char* Ak = Ab + (size_t)(((s2 >> 3) * 16) + (s2 & 7)) * 8192;
      glds16(Ak + t * 16, slotn + t * 16);
      glds16(Ak + t * 16 + 4096, slotn + t * 16 + 4096);
      const char* Bk = Bb + (size_t)(s2 & 7) * 1024;
      glds16(Bk + (size_t)w * 8192 + L * 16, slotn + 8192 + t * 16);
      glds16(Bk + (size_t)(w + 4) * 8192 + L * 16, slotn + 8192 + t * 16 + 4096);
    }
    char* slotc = smem + (st % 3) * 16384;
    bf16x8 af[4], bfr[4];
#pragma unroll
    for (int i = 0; i < 4; ++i) {
      af[i] = *(const bf16x8*)(slotc + (wrow * 4 + i) * 1024 + L * 16);
      bfr[i] = *(const bf16x8*)(slotc + 8192 + (wcol * 4 + i) * 1024 + L * 16);
    }
#pragma unroll
    for (int i = 0; i < 4; ++i)
#pragma unroll
      for (int j = 0; j < 4; ++j)
        acc[i][j] = __builtin_amdgcn_mfma_f32_16x16x32_bf16(af[i], bfr[j], acc[i][j], 0, 0, 0);
  }

  float* O = out + (size_t)tb * TBC;
  const float* sbn = bnw + 3 * 512;
  const int rbase = rt * 128;
#pragma unroll
  for (int i = 0; i < 4; ++i) {
    int co0 = rbase + wrow * 64 + i * 16 + ((L >> 4) << 2);
#pragma unroll
    for (int j = 0; j < 4; ++j) {
      int n = n0 + wcol * 64 + j * 16 + (L & 15);
      if (n < N_) {
#pragma unroll
        for (int r = 0; r < 4; ++r) {
          int co = co0 + r;
          float y = acc[i][j][r] * 0.125f;
          O[(size_t)co * N_ + n] = __fadd_rn(__fmul_rn(y, sbn[co]), sbn[256 + co]);
        }
      }
    }
  }
}

// ---------------------------------------------------------------------------
extern "C" void kernel_launch(void* const* d_in, const int* in_sizes, int n_in,
                              void* d_out, int out_size, void* d_ws, size_t ws_size,
                              hipStream_t stream) {
  const float* x   = (const float*)d_in[0];
  const float* qw  = (const float*)d_in[1];
  const float* qbn = (const float*)d_in[2];
  const float* kw  = (const float*)d_in[3];
  const float* kbn = (const float*)d_in[4];
  const float* vw  = (const float*)d_in[5];
  const float* vbn = (const float*)d_in[6];
  const float* pw  = (const float*)d_in[7];
  const float* pbn = (const float*)d_in[8];
  float* out = (float*)d_out;

  uint8_t* ws = (uint8_t*)d_ws;
  float* bnw           = (float*)ws;                           // 8 KB
  unsigned short* wsp  = (unsigned short*)(ws + 8192);         // 1.57 MB
  unsigned short* xsb  = (unsigned short*)(ws + 1581056);      // 52.43 MB
  uint8_t* qsb         = ws + 54009856;                        // 26.21 MB u8 blocked q
  uint8_t* ksp         = ws + 80224256;                        // 25.69 MB
  uint8_t* vsp         = ws + 105914368;                       // 25.69 MB
  int* kvg             = (int*)(ws + 131604480);               // 1.05 MB
  unsigned short* kvimg = (unsigned short*)(ws + 132653056);   // 1.57 MB -> ends 134.2 MB
  unsigned short* osb  = xsb;   // alias: xsb dead after qkv

  prep_all<<<1057, 256, 0, stream>>>(qbn, kbn, vbn, pbn, qw, kw, vw, pw, bnw, wsp, kvg);
  quant_x_t<<<dim3(49, 32), 256, 0, stream>>>(x, xsb);
  qkv_mfma_sw<<<3840, 256, 0, stream>>>(xsb, wsp, bnw, qsb, ksp, vsp);
  attn_kv<<<dim3(8, 32, PARTS), 256, 0, stream>>>(ksp, vsp, kvg);
  kv_finish<<<256, 256, 0, stream>>>(kvg, kvimg);
  attn_o_mfma<<<800, 256, 0, stream>>>(qsb, kvimg, osb);
  out_mfma_sw<<<1600, 256, 0, stream>>>(osb, wsp, bnw, out);
}

// Round 10
// 399.620 us; speedup vs baseline: 1.0089x; 1.0089x over previous
//
#include <hip/hip_runtime.h>
#include <stdint.h>

#define TB_ 32
#define C_ 256
#define N_ 3136
#define TBC (C_ * N_)            // 802816 elems per (t,b) per 256-ch tensor
#define ACT_SZ (TB_ * TBC)       // 25690112
#define XSB_TB 819200            // elems per tb in blocked layouts (200 groups * 4096)
#define PARTS 7
#define CHUNK 448                // 3136/7, multiple of 16

typedef __attribute__((ext_vector_type(8))) short bf16x8;
typedef __attribute__((ext_vector_type(4))) float f32x4;

__device__ __forceinline__ void glds16(const void* gp, void* lp) {
  __builtin_amdgcn_global_load_lds(
      (const __attribute__((address_space(1))) unsigned int*)gp,
      (__attribute__((address_space(3))) unsigned int*)lp, 16, 0, 0);
}

__device__ __forceinline__ unsigned short bf16rn(float f, float* val) {
  unsigned b = __float_as_uint(f);
  unsigned r = (b + 0x7fffu + ((b >> 16) & 1u)) >> 16;
  *val = __uint_as_float(r << 16);
  return (unsigned short)r;
}

__device__ __forceinline__ int dot4u(unsigned a, unsigned b, int c) {
  c += (int)(a & 255u)         * (int)(b & 255u);
  c += (int)((a >> 8) & 255u)  * (int)((b >> 8) & 255u);
  c += (int)((a >> 16) & 255u) * (int)((b >> 16) & 255u);
  c += (int)(a >> 24)          * (int)(b >> 24);
  return c;
}

__device__ __forceinline__ int dot4(unsigned a, unsigned b, int c) {
#if defined(__has_builtin)
#if __has_builtin(__builtin_amdgcn_sdot4)
  return __builtin_amdgcn_sdot4((int)a, (int)b, c, false);
#else
  return dot4u(a, b, c);
#endif
#else
  return dot4u(a, b, c);
#endif
}

// ---------------------------------------------------------------------------
// K0: fused prep — bx 0: BN fold; 1..1024: weight split; 1025..1056: kvg zero
// ---------------------------------------------------------------------------
__global__ __launch_bounds__(256) void prep_all(
    const float* __restrict__ qbn, const float* __restrict__ kbn,
    const float* __restrict__ vbn, const float* __restrict__ pbn,
    const float* __restrict__ qw, const float* __restrict__ kw,
    const float* __restrict__ vw, const float* __restrict__ pw,
    float* __restrict__ bnw, unsigned short* __restrict__ wsp,
    int* __restrict__ kvg) {
  const int bx = blockIdx.x;
  const int t = threadIdx.x;
  if (bx == 0) {
    const float* ps[4] = {qbn, kbn, vbn, pbn};
#pragma unroll
    for (int i = 0; i < 4; ++i) {
      const float* p = ps[i];
      float g = p[t], be = p[256 + t], mn = p[512 + t], vr = p[768 + t];
      float s = g / sqrtf(vr + 1e-5f);
      float b = __fsub_rn(be, __fmul_rn(mn, s));
      bnw[i * 512 + t] = s;
      bnw[i * 512 + 256 + t] = b;
    }
  } else if (bx <= 1024) {
    const float* Ws[4] = {qw, kw, vw, pw};
    int id = bx - 1, co = id & 255, m = id >> 8;
    float w = Ws[m][co * 256 + t];
    float h1, h2, h3r;
    unsigned short u1 = bf16rn(w, &h1);
    float r1 = __fsub_rn(w, h1);
    unsigned short u2 = bf16rn(r1, &h2);
    float r2 = __fsub_rn(r1, h2);
    unsigned short u3 = bf16rn(r2, &h3r);   // exact: r2 has <=8 significant bits
    int rt = co >> 7, ks = t >> 5;
    int lane = (co & 15) + 16 * ((t >> 3) & 3);
    unsigned short us[3] = {u1, u2, u3};
#pragma unroll
    for (int sp = 0; sp < 3; ++sp) {
      size_t off = (size_t)((((m * 3 + sp) * 2 + rt) * 8 + ks)) * 4096 + lane * 8 + (t & 7);
      wsp[off] = us[sp];
    }
  } else {
    int tb = bx - 1025;
    int4* p = (int4*)(kvg + (size_t)tb * 8192);
    for (int i = t; i < 2048; i += 256) p[i] = make_int4(0, 0, 0, 0);
  }
}

// ---------------------------------------------------------------------------
// K1: x -> spikes (bf16, exact 0..8) in blocked B-fragment layout (float4 loads)
// ---------------------------------------------------------------------------
__global__ __launch_bounds__(256) void quant_x_t(const float* __restrict__ x,
                                                 unsigned short* __restrict__ xsb) {
  __shared__ unsigned short s[64 * 68];
  const int t = threadIdx.x;
  const int n0 = blockIdx.x * 64;
  const int tb = blockIdx.y;
  const float* X = x + (size_t)tb * TBC;
  const int nl = t & 63, cq = t >> 6;
  const int c16 = t >> 4, p4 = (t & 15) * 4;

  unsigned short* dstb = xsb + (size_t)tb * XSB_TB;
  for (int cb = 0; cb < 4; ++cb) {
    int cbase = cb * 64;
#pragma unroll
    for (int i = 0; i < 4; ++i) {
      int c = i * 16 + c16;
      float4 v = *(const float4*)&X[(size_t)(cbase + c) * N_ + n0 + p4];
      unsigned short r0 = (unsigned short)(__float_as_uint(fminf(fmaxf(rintf(v.x), 0.f), 8.f)) >> 16);
      unsigned short r1 = (unsigned short)(__float_as_uint(fminf(fmaxf(rintf(v.y), 0.f), 8.f)) >> 16);
      unsigned short r2 = (unsigned short)(__float_as_uint(fminf(fmaxf(rintf(v.z), 0.f), 8.f)) >> 16);
      unsigned short r3 = (unsigned short)(__float_as_uint(fminf(fmaxf(rintf(v.w), 0.f), 8.f)) >> 16);
      uint2 pk2;
      pk2.x = (unsigned)r0 | ((unsigned)r1 << 16);
      pk2.y = (unsigned)r2 | ((unsigned)r3 << 16);
      *(uint2*)&s[c * 68 + p4] = pk2;
    }
    __syncthreads();
#pragma unroll 2
    for (int j = 0; j < 2; ++j) {
      int ccl = j * 4 + cq;
      int cc = cb * 8 + ccl;
      unsigned short v8[8];
#pragma unroll
      for (int d = 0; d < 8; ++d) v8[d] = s[(ccl * 8 + d) * 68 + nl];
      int n = n0 + nl;
      uint4 pk;
      pk.x = (unsigned)v8[0] | ((unsigned)v8[1] << 16);
      pk.y = (unsigned)v8[2] | ((unsigned)v8[3] << 16);
      pk.z = (unsigned)v8[4] | ((unsigned)v8[5] << 16);
      pk.w = (unsigned)v8[6] | ((unsigned)v8[7] << 16);
      *(uint4*)&dstb[(size_t)(n >> 4) * 4096 + cc * 128 + (n & 15) * 8] = pk;
    }
    __syncthreads();
  }
}

// ---------------------------------------------------------------------------
// K2: fused q/k/v GEMM. Round-16: mixed-depth ring — A (L2-hot weights,
// ~200cy) 2-deep at distance-1; B (L3/HBM activations, 400-900cy) 3-deep at
// distance-2. LDS 16+24 = 40KB -> 4 blocks/CU (was 3 at 48KB). Step body:
// {vmcnt(2); s_barrier; issue A(st+1)->Aslot[(st+1)&1]; issue B(st+2)->
// Bslot[(st+2)%3]; compute st}. FIFO: newest 2 ops at step-top are B(st+1),
// so vmcnt(2) retires exactly A(st) (1 step old) and B(st) (2 steps old).
// WAR: post-barrier writes into slots last read at compute(st-1), which
// completed before barrier(st) — proven argument. Per-acc (sp,ks) MFMA
// chain unchanged -> bitwise-identical. Tile/fragment math = proven 128x128.
// ---------------------------------------------------------------------------
__global__ __launch_bounds__(256) void qkv_mfma_sw(
    const unsigned short* __restrict__ xsb, const unsigned short* __restrict__ wsp,
    const float* __restrict__ bnw,
    uint8_t* __restrict__ qsb, uint8_t* __restrict__ ks_, uint8_t* __restrict__ vs) {
  __shared__ __align__(16) char smem[40960];   // A: 2 x 8KB @0, B: 3 x 8KB @16384
  char* const Bbase = smem + 16384;
  const int t = threadIdx.x;
  const int L = t & 63, w = t >> 6;
  const int wrow = w >> 1, wcol = w & 1;
  const int b = blockIdx.x;
  const int oct = b / 48, rem = b % 48;
  const int s = rem >> 3, gl = rem & 7;
  const int g = oct * 8 + gl;
  const int ntile = g % 25, tb = g / 25;
  const int conv = s >> 1, rt = s & 1;
  const int n0 = ntile * 128;

  const char* Bb = (const char*)(xsb + (size_t)tb * XSB_TB) + (size_t)ntile * 65536;
  const char* Ab = (const char*)wsp + ((size_t)(conv * 3) * 16 + rt * 8) * 8192;

  f32x4 acc[4][4];
#pragma unroll
  for (int i = 0; i < 4; ++i)
#pragma unroll
    for (int j = 0; j < 4; ++j) acc[i][j] = (f32x4){0.f, 0.f, 0.f, 0.f};

  // prologue (issue order matters for vmcnt counting): B(0), A(0), B(1)
  glds16(Bb + (size_t)w * 8192 + L * 16, Bbase + t * 16);
  glds16(Bb + (size_t)(w + 4) * 8192 + L * 16, Bbase + t * 16 + 4096);
  glds16(Ab + t * 16, smem + t * 16);
  glds16(Ab + t * 16 + 4096, smem + t * 16 + 4096);
  {
    const char* Bk1 = Bb + 1024;
    glds16(Bk1 + (size_t)w * 8192 + L * 16, Bbase + 8192 + t * 16);
    glds16(Bk1 + (size_t)(w + 4) * 8192 + L * 16, Bbase + 8192 + t * 16 + 4096);
  }

  // step st: sp = st>>3, ks = st&7  (24 steps)
#pragma unroll 1
  for (int st = 0; st < 24; ++st) {
    if (st < 23) {
      asm volatile("s_waitcnt vmcnt(2)" ::: "memory");   // retires A(st), B(st)
    } else {
      asm volatile("s_waitcnt vmcnt(0)" ::: "memory");
    }
    __builtin_amdgcn_s_barrier();
    const int s1 = st + 1;
    if (s1 < 24) {   // A at distance-1 (issue FIRST so B(st+2) stays newest)
      char* an = smem + (s1 & 1) * 8192;
      const char* Ak = Ab + (size_t)(((s1 >> 3) * 16) + (s1 & 7)) * 8192;
      glds16(Ak + t * 16, an + t * 16);
      glds16(Ak + t * 16 + 4096, an + t * 16 + 4096);
    }
    const int s2 = st + 2;
    if (s2 < 24) {   // B at distance-2
      char* bn = Bbase + (s2 % 3) * 8192;
      const char* Bk = Bb + (size_t)(s2 & 7) * 1024;
      glds16(Bk + (size_t)w * 8192 + L * 16, bn + t * 16);
      glds16(Bk + (size_t)(w + 4) * 8192 + L * 16, bn + t * 16 + 4096);
    }
    char* ac = smem + (st & 1) * 8192;
    char* bc = Bbase + (st % 3) * 8192;
    bf16x8 af[4], bfr[4];
#pragma unroll
    for (int i = 0; i < 4; ++i) {
      af[i] = *(const bf16x8*)(ac + (wrow * 4 + i) * 1024 + L * 16);
      bfr[i] = *(const bf16x8*)(bc + (wcol * 4 + i) * 1024 + L * 16);
    }
#pragma unroll
    for (int i = 0; i < 4; ++i)
#pragma unroll
      for (int j = 0; j < 4; ++j)
        acc[i][j] = __builtin_amdgcn_mfma_f32_16x16x32_bf16(af[i], bfr[j], acc[i][j], 0, 0, 0);
  }

  const float* sbn = bnw + conv * 512;
  const int rbase = rt * 128;
  if (conv == 0) {
    uint8_t* qtb = qsb + (size_t)tb * XSB_TB;   // u8 blocked, same group layout
#pragma unroll
    for (int i = 0; i < 4; ++i) {
      int co0 = rbase + wrow * 64 + i * 16 + ((L >> 4) << 2);
      float s0 = sbn[co0], b0 = sbn[256 + co0];
      float s1 = sbn[co0 + 1], b1 = sbn[256 + co0 + 1];
      float s2v = sbn[co0 + 2], b2 = sbn[256 + co0 + 2];
      float s3 = sbn[co0 + 3], b3 = sbn[256 + co0 + 3];
#pragma unroll
      for (int j = 0; j < 4; ++j) {
        int n = n0 + wcol * 64 + j * 16 + (L & 15);
        if (n < N_) {
          float ss[4] = {s0, s1, s2v, s3}, bb[4] = {b0, b1, b2, b3};
          unsigned wb = 0;
#pragma unroll
          for (int r = 0; r < 4; ++r) {
            float y = acc[i][j][r] * 0.125f;
            float tt = __fadd_rn(__fmul_rn(y, ss[r]), bb[r]);
            float rr = fminf(fmaxf(rintf(tt), 0.f), 8.f);
            wb |= ((unsigned)(uint8_t)rr) << (8 * r);
          }
          *(unsigned*)&qtb[(size_t)(n >> 4) * 4096 + (co0 >> 3) * 128 + (n & 15) * 8 + (co0 & 7)] = wb;
        }
      }
    }
  } else {
    uint8_t* outp = (conv == 1 ? ks_ : vs) + (size_t)tb * TBC;
#pragma unroll
    for (int i = 0; i < 4; ++i) {
      int co0 = rbase + wrow * 64 + i * 16 + ((L >> 4) << 2);
#pragma unroll
      for (int j = 0; j < 4; ++j) {
        int n = n0 + wcol * 64 + j * 16 + (L & 15);
        if (n < N_) {
#pragma unroll
          for (int r = 0; r < 4; ++r) {
            int co = co0 + r;
            float y = acc[i][j][r] * 0.125f;
            float tt = __fadd_rn(__fmul_rn(y, sbn[co]), sbn[256 + co]);
            float rr = fminf(fmaxf(rintf(tt), 0.f), 8.f);
            outp[(size_t)co * N_ + n] = (uint8_t)rr;
          }
        }
      }
    }
  }
}

// ---------------------------------------------------------------------------
// K3: partial kv = k^T v, exact i32 atomics. sv XOR swizzle (verified):
// v-read conflict 4-way -> 2-way. grid (8,32,PARTS)
// ---------------------------------------------------------------------------
__global__ __launch_bounds__(256) void attn_kv(
    const uint8_t* __restrict__ ks, const uint8_t* __restrict__ vs,
    int* __restrict__ kvg) {
  const int h = blockIdx.x, tb = blockIdx.y, part = blockIdx.z;
  const int tid = threadIdx.x;
  __shared__ unsigned sk[32][68];
  __shared__ unsigned sv[32][68];
  const uint8_t* K = ks + (size_t)tb * TBC + h * 32 * N_;
  const uint8_t* V = vs + (size_t)tb * TBC + h * 32 * N_;
  const int d0 = (tid >> 4) * 2;
  const int e0 = (tid & 15) * 2;
  const int vsw = ((e0 >> 1) & 7) << 2;   // read-side XOR for rows e0, e0+1
  const int pbase = part * CHUNK;
  const int pend = pbase + CHUNK;
  int acc[2][2] = {};

  for (int nt = 0; nt < 2; ++nt) {
    int n0 = pbase + nt * 256;
    if (n0 >= pend) break;
    if (nt) __syncthreads();
#pragma unroll
    for (int i = 0; i < 8; ++i) {
      int idx = tid + i * 256;
      int d = idx >> 6, w2 = idx & 63;
      int n = n0 + w2 * 4;
      unsigned kw_ = 0, vw_ = 0;
      if (n < pend) {
        kw_ = *(const unsigned*)&K[d * N_ + n];
        vw_ = *(const unsigned*)&V[d * N_ + n];
      }
      sk[d][w2] = kw_;
      sv[d][w2 ^ (((d >> 1) & 7) << 2)] = vw_;
    }
    __syncthreads();
#pragma unroll
    for (int w2 = 0; w2 < 64; w2 += 4) {
      uint4 ka = *(const uint4*)&sk[d0][w2];
      uint4 kb = *(const uint4*)&sk[d0 + 1][w2];
      uint4 va = *(const uint4*)&sv[e0][w2 ^ vsw];
      uint4 vb = *(const uint4*)&sv[e0 + 1][w2 ^ vsw];
      unsigned kwds[2][4] = {{ka.x, ka.y, ka.z, ka.w}, {kb.x, kb.y, kb.z, kb.w}};
      unsigned vwds[2][4] = {{va.x, va.y, va.z, va.w}, {vb.x, vb.y, vb.z, vb.w}};
#pragma unroll
      for (int di = 0; di < 2; ++di)
#pragma unroll
        for (int ej = 0; ej < 2; ++ej)
#pragma unroll
          for (int c = 0; c < 4; ++c)
            acc[di][ej] = dot4(kwds[di][c], vwds[ej][c], acc[di][ej]);
    }
  }
  int* dst = kvg + ((size_t)(tb * 8 + h)) * 1024;
  atomicAdd(&dst[d0 * 32 + e0], acc[0][0]);
  atomicAdd(&dst[d0 * 32 + e0 + 1], acc[0][1]);
  atomicAdd(&dst[(d0 + 1) * 32 + e0], acc[1][0]);
  atomicAdd(&dst[(d0 + 1) * 32 + e0 + 1], acc[1][1]);
}

// ---------------------------------------------------------------------------
// K3b: split kv ints (< 2^18, nonneg) into 3 truncation-exact bf16 parts,
// laid out as MFMA A-fragment images. 256 blocks (widened).
// ---------------------------------------------------------------------------
__global__ __launch_bounds__(256) void kv_finish(const int* __restrict__ kvg,
                                                 unsigned short* __restrict__ kvimg) {
  const int bx = blockIdx.x, t = threadIdx.x;
  const int tb = bx >> 3;
  const int base = (bx & 7) * 1024;
  const int* src = kvg + (size_t)tb * 8192;
  unsigned short* dst = kvimg + (size_t)tb * 24576;
#pragma unroll
  for (int i = 0; i < 4; ++i) {
    int idx = base + t + i * 256;
    int h = idx >> 10, rem = idx & 1023, d = rem >> 5, e = rem & 31;
    int v = src[idx];
    int b1 = (v > 0) ? (32 - __clz(v)) : 0;
    int sh1 = b1 > 8 ? b1 - 8 : 0;
    int hi = (v >> sh1) << sh1;
    int r1 = v - hi;
    int b2 = (r1 > 0) ? (32 - __clz(r1)) : 0;
    int sh2 = b2 > 8 ? b2 - 8 : 0;
    int mid = (r1 >> sh2) << sh2;
    int r2 = r1 - mid;
    int parts[3] = {hi, mid, r2};
    int mtile = e >> 4, lane = (e & 15) + 16 * (d >> 3), j = d & 7;
#pragma unroll
    for (int sp = 0; sp < 3; ++sp) {
      float f = (float)parts[sp];   // exact: <=8 significant bits
      dst[(size_t)h * 3072 + (sp * 2 + mtile) * 512 + lane * 8 + j] =
          (unsigned short)(__float_as_uint(f) >> 16);
    }
  }
}

// ---------------------------------------------------------------------------
// K3c: o = quant(q . kv * scale) via bf16 MFMA. Double-buffered head
// pipeline (1 barrier/head, T14 issue-early/write-late). grid 800.
// ---------------------------------------------------------------------------
__global__ __launch_bounds__(256) void attn_o_mfma(
    const uint8_t* __restrict__ qsb, const unsigned short* __restrict__ kvimg,
    unsigned short* __restrict__ osb) {
  __shared__ __align__(16) char smem[28672];   // 2 x (8KB B-image + 6KB A-images)
  const int t = threadIdx.x;
  const int L = t & 63, wv = t >> 6;
  const int b = blockIdx.x;
  const int ntile = b % 25, tb = b / 25;
  const uint8_t* Q = qsb + (size_t)tb * XSB_TB + (size_t)ntile * 8 * 4096;
  const unsigned short* KV = kvimg + (size_t)tb * 24576;
  unsigned short* osb_tb = osb + (size_t)tb * XSB_TB;
  const float cscale = (float)(0.3535533905932738 / 512.0);

  // stage(0) fully (loads + writes) into buffer 0
  {
    char* smB = smem;
    char* smA = smem + 8192;
    const char* Ah = (const char*)KV;
    glds16(Ah + t * 16, smA + t * 16);
    if (t < 128) glds16(Ah + 4096 + t * 16, smA + 4096 + t * 16);
#pragma unroll
    for (int it = 0; it < 4; ++it) {
      int w2 = t + it * 256;
      int gl2 = w2 >> 7, wl = w2 & 127, ccp = wl >> 5;
      int rem = (w2 * 4) & 127, n16 = rem >> 3, k7b = rem & 7;
      unsigned wd = *(const unsigned*)&Q[(size_t)gl2 * 4096 + (0 * 4 + ccp) * 128 + n16 * 8 + k7b];
      unsigned short* ds = (unsigned short*)smB + gl2 * 512 + (ccp * 16 + n16) * 8 + k7b;
      float f0 = (float)(wd & 255u), f1 = (float)((wd >> 8) & 255u);
      float f2 = (float)((wd >> 16) & 255u), f3 = (float)(wd >> 24);
      uint2 pk;
      pk.x = (__float_as_uint(f0) >> 16) | ((__float_as_uint(f1) >> 16) << 16);
      pk.y = (__float_as_uint(f2) >> 16) | ((__float_as_uint(f3) >> 16) << 16);
      *(uint2*)ds = pk;
    }
  }

#pragma unroll 1
  for (int h = 0; h < 8; ++h) {
    __syncthreads();   // drains stage(h) glds16 + ds_writes; guards buffer reuse
    char* cur = smem + (h & 1) * 14336;
    char* smB = cur;
    char* smA = cur + 8192;
    // read B frags of head h
    bf16x8 bfr[2];
#pragma unroll
    for (int jj = 0; jj < 2; ++jj)
      bfr[jj] = *(const bf16x8*)(smB + (wv * 2 + jj) * 1024 + L * 16);
    // T14 issue-early: A-images(h+1) via glds16; Q words(h+1) into regs
    unsigned wd[4];
    if (h < 7) {
      char* alt = smem + ((h + 1) & 1) * 14336;
      const char* Ah = (const char*)(KV + (size_t)(h + 1) * 3072);
      glds16(Ah + t * 16, alt + 8192 + t * 16);
      if (t < 128) glds16(Ah + 4096 + t * 16, alt + 8192 + 4096 + t * 16);
#pragma unroll
      for (int it = 0; it < 4; ++it) {
        int w2 = t + it * 256;
        int gl2 = w2 >> 7, wl = w2 & 127, ccp = wl >> 5;
        int rem = (w2 * 4) & 127, n16 = rem >> 3, k7b = rem & 7;
        wd[it] = *(const unsigned*)&Q[(size_t)gl2 * 4096 + ((h + 1) * 4 + ccp) * 128 + n16 * 8 + k7b];
      }
    }
    // MFMAs of head h
    f32x4 acc[2][2];
#pragma unroll
    for (int i = 0; i < 2; ++i)
#pragma unroll
      for (int jj = 0; jj < 2; ++jj) acc[i][jj] = (f32x4){0.f, 0.f, 0.f, 0.f};
#pragma unroll
    for (int sp = 0; sp < 3; ++sp) {
      bf16x8 a0 = *(const bf16x8*)(smA + (sp * 2 + 0) * 1024 + L * 16);
      bf16x8 a1 = *(const bf16x8*)(smA + (sp * 2 + 1) * 1024 + L * 16);
#pragma unroll
      for (int jj = 0; jj < 2; ++jj) {
        acc[0][jj] = __builtin_amdgcn_mfma_f32_16x16x32_bf16(a0, bfr[jj], acc[0][jj], 0, 0, 0);
        acc[1][jj] = __builtin_amdgcn_mfma_f32_16x16x32_bf16(a1, bfr[jj], acc[1][jj], 0, 0, 0);
      }
    }
    // T14 write-late: unpack Q(h+1) -> alt B-image
    if (h < 7) {
      char* alt = smem + ((h + 1) & 1) * 14336;
#pragma unroll
      for (int it = 0; it < 4; ++it) {
        int w2 = t + it * 256;
        int gl2 = w2 >> 7, wl = w2 & 127, ccp = wl >> 5;
        int rem = (w2 * 4) & 127, n16 = rem >> 3, k7b = rem & 7;
        unsigned short* ds = (unsigned short*)alt + gl2 * 512 + (ccp * 16 + n16) * 8 + k7b;
        float f0 = (float)(wd[it] & 255u), f1 = (float)((wd[it] >> 8) & 255u);
        float f2 = (float)((wd[it] >> 16) & 255u), f3 = (float)(wd[it] >> 24);
        uint2 pk;
        pk.x = (__float_as_uint(f0) >> 16) | ((__float_as_uint(f1) >> 16) << 16);
        pk.y = (__float_as_uint(f2) >> 16) | ((__float_as_uint(f3) >> 16) << 16);
        *(uint2*)ds = pk;
      }
    }
    // epilogue of head h
#pragma unroll
    for (int i = 0; i < 2; ++i) {
      int c0 = h * 32 + i * 16 + ((L >> 4) << 2);
#pragma unroll
      for (int jj = 0; jj < 2; ++jj) {
        int n = ntile * 128 + (wv * 2 + jj) * 16 + (L & 15);
        if (n < N_) {
          unsigned short u[4];
#pragma unroll
          for (int r = 0; r < 4; ++r) {
            float of = acc[i][jj][r] * cscale;
            float rr = fminf(fmaxf(rintf(of), 0.f), 8.f);
            u[r] = (unsigned short)(__float_as_uint(rr) >> 16);
          }
          uint2 pk;
          pk.x = (unsigned)u[0] | ((unsigned)u[1] << 16);
          pk.y = (unsigned)u[2] | ((unsigned)u[3] << 16);
          *(uint2*)&osb_tb[(size_t)(n >> 4) * 4096 + (c0 >> 3) * 128 + (n & 15) * 8 + (c0 & 7)] = pk;
        }
      }
    }
  }
}

// ---------------------------------------------------------------------------
// K4: out = BN(pw @ os/8) via bf16 MFMA, 2 splits. Round-16: same mixed-
// depth ring as K2 (A 2-deep dist-1, B 3-deep dist-2, 40KB, vmcnt(2)).
// ---------------------------------------------------------------------------
__global__ __launch_bounds__(256) void out_mfma_sw(
    const unsigned short* __restrict__ osb, const unsigned short* __restrict__ wsp,
    const float* __restrict__ bnw, float* __restrict__ out) {
  __shared__ __align__(16) char smem[40960];   // A: 2 x 8KB @0, B: 3 x 8KB @16384
  char* const Bbase = smem + 16384;
  const int t = threadIdx.x;
  const int L = t & 63, w = t >> 6;
  const int wrow = w >> 1, wcol = w & 1;
  const int b = blockIdx.x;
  const int oct = b / 16, rem = b % 16;
  const int rt = rem >> 3, gl = rem & 7;
  const int g = oct * 8 + gl;
  const int ntile = g % 25, tb = g / 25;
  const int n0 = ntile * 128;
  const char* Bb = (const char*)(osb + (size_t)tb * XSB_TB) + (size_t)ntile * 65536;
  const char* Ab = (const char*)wsp + ((size_t)9 * 16 + rt * 8) * 8192;

  f32x4 acc[4][4];
#pragma unroll
  for (int i = 0; i < 4; ++i)
#pragma unroll
    for (int j = 0; j < 4; ++j) acc[i][j] = (f32x4){0.f, 0.f, 0.f, 0.f};

  // prologue: B(0), A(0), B(1)
  glds16(Bb + (size_t)w * 8192 + L * 16, Bbase + t * 16);
  glds16(Bb + (size_t)(w + 4) * 8192 + L * 16, Bbase + t * 16 + 4096);
  glds16(Ab + t * 16, smem + t * 16);
  glds16(Ab + t * 16 + 4096, smem + t * 16 + 4096);
  {
    const char* Bk1 = Bb + 1024;
    glds16(Bk1 + (size_t)w * 8192 + L * 16, Bbase + 8192 + t * 16);
    glds16(Bk1 + (size_t)(w + 4) * 8192 + L * 16, Bbase + 8192 + t * 16 + 4096);
  }

  // step st: sp = st>>3, ks = st&7  (16 steps)
#pragma unroll 1
  for (int st = 0; st < 16; ++st) {
    if (st < 15) {
      asm volatile("s_waitcnt vmcnt(2)" ::: "memory");
    } else {
      asm volatile("s_waitcnt vmcnt(0)" ::: "memory");
    }
    __builtin_amdgcn_s_barrier();
    const int s1 = st + 1;
    if (s1 < 16) {
      char* an = smem + (s1 & 1) * 8192;
      const char* Ak = Ab + (size_t)(((s1 >> 3) * 16) + (s1 & 7)) * 8192;
      glds16(Ak + t * 16, an + t * 16);
      glds16(Ak + t * 16 + 4096, an + t * 16 + 4096);
    }
    const int s2 = st + 2;
    if (s2 < 16) {
      char* bn = Bbase + (s2 % 3) * 8192;
      const char* Bk = Bb + (size_t)(s2 & 7) * 1024;
      glds16(Bk + (size_t)w * 8192 + L * 16, bn + t * 16);
      glds16(Bk + (size_t)(w + 4) * 8192 + L * 16, bn + t * 16 + 4096);
    }
    char* ac = smem + (st & 1) * 8192;
    char* bc = Bbase + (st % 3) * 8192;
    bf16x8 af[4], bfr[4];
#pragma unroll
    for (int i = 0; i < 4; ++i) {
      af[i] = *(const bf16x8*)(ac + (wrow * 4 + i) * 1024 + L * 16);
      bfr[i] = *(const bf16x8*)(bc + (wcol * 4 + i) * 1024 + L * 16);
    }
#pragma unroll
    for (int i = 0; i < 4; ++i)
#pragma unroll
      for (int j = 0; j < 4; ++j)
        acc[i][j] = __builtin_amdgcn_mfma_f32_16x16x32_bf16(af[i], bfr[j], acc[i][j], 0, 0, 0);
  }

  float* O = out + (size_t)tb * TBC;
  const float* sbn = bnw + 3 * 512;
  const int rbase = rt * 128;
#pragma unroll
  for (int i = 0; i < 4; ++i) {
    int co0 = rbase + wrow * 64 + i * 16 + ((L >> 4) << 2);
#pragma unroll
    for (int j = 0; j < 4; ++j) {
      int n = n0 + wcol * 64 + j * 16 + (L & 15);
      if (n < N_) {
#pragma unroll
        for (int r = 0; r < 4; ++r) {
          int co = co0 + r;
          float y = acc[i][j][r] * 0.125f;
          O[(size_t)co * N_ + n] = __fadd_rn(__fmul_rn(y, sbn[co]), sbn[256 + co]);
        }
      }
    }
  }
}

// ---------------------------------------------------------------------------
extern "C" void kernel_launch(void* const* d_in, const int* in_sizes, int n_in,
                              void* d_out, int out_size, void* d_ws, size_t ws_size,
                              hipStream_t stream) {
  const float* x   = (const float*)d_in[0];
  const float* qw  = (const float*)d_in[1];
  const float* qbn = (const float*)d_in[2];
  const float* kw  = (const float*)d_in[3];
  const float* kbn = (const float*)d_in[4];
  const float* vw  = (const float*)d_in[5];
  const float* vbn = (const float*)d_in[6];
  const float* pw  = (const float*)d_in[7];
  const float* pbn = (const float*)d_in[8];
  float* out = (float*)d_out;

  uint8_t* ws = (uint8_t*)d_ws;
  float* bnw           = (float*)ws;                           // 8 KB
  unsigned short* wsp  = (unsigned short*)(ws + 8192);         // 1.57 MB
  unsigned short* xsb  = (unsigned short*)(ws + 1581056);      // 52.43 MB
  uint8_t* qsb         = ws + 54009856;                        // 26.21 MB u8 blocked q
  uint8_t* ksp         = ws + 80224256;                        // 25.69 MB
  uint8_t* vsp         = ws + 105914368;                       // 25.69 MB
  int* kvg             = (int*)(ws + 131604480);               // 1.05 MB
  unsigned short* kvimg = (unsigned short*)(ws + 132653056);   // 1.57 MB -> ends 134.2 MB
  unsigned short* osb  = xsb;   // alias: xsb dead after qkv

  prep_all<<<1057, 256, 0, stream>>>(qbn, kbn, vbn, pbn, qw, kw, vw, pw, bnw, wsp, kvg);
  quant_x_t<<<dim3(49, 32), 256, 0, stream>>>(x, xsb);
  qkv_mfma_sw<<<4800, 256, 0, stream>>>(xsb, wsp, bnw, qsb, ksp, vsp);
  attn_kv<<<dim3(8, 32, PARTS), 256, 0, stream>>>(ksp, vsp, kvg);
  kv_finish<<<256, 256, 0, stream>>>(kvg, kvimg);
  attn_o_mfma<<<800, 256, 0, stream>>>(qsb, kvimg, osb);
  out_mfma_sw<<<1600, 256, 0, stream>>>(osb, wsp, bnw, out);
}

// Round 11
// 386.448 us; speedup vs baseline: 1.0433x; 1.0341x over previous
//
#include <hip/hip_runtime.h>
#include <stdint.h>

#define TB_ 32
#define C_ 256
#define N_ 3136
#define TBC (C_ * N_)            // 802816 elems per (t,b) per 256-ch tensor
#define ACT_SZ (TB_ * TBC)       // 25690112
#define XSB_TB 819200            // elems per tb in blocked layouts (200 groups * 4096)
#define PARTS 7
#define CHUNK 448                // 3136/7, multiple of 16

typedef __attribute__((ext_vector_type(8))) short bf16x8;
typedef __attribute__((ext_vector_type(4))) float f32x4;

__device__ __forceinline__ void glds16(const void* gp, void* lp) {
  __builtin_amdgcn_global_load_lds(
      (const __attribute__((address_space(1))) unsigned int*)gp,
      (__attribute__((address_space(3))) unsigned int*)lp, 16, 0, 0);
}

__device__ __forceinline__ unsigned short bf16rn(float f, float* val) {
  unsigned b = __float_as_uint(f);
  unsigned r = (b + 0x7fffu + ((b >> 16) & 1u)) >> 16;
  *val = __uint_as_float(r << 16);
  return (unsigned short)r;
}

__device__ __forceinline__ int dot4u(unsigned a, unsigned b, int c) {
  c += (int)(a & 255u)         * (int)(b & 255u);
  c += (int)((a >> 8) & 255u)  * (int)((b >> 8) & 255u);
  c += (int)((a >> 16) & 255u) * (int)((b >> 16) & 255u);
  c += (int)(a >> 24)          * (int)(b >> 24);
  return c;
}

__device__ __forceinline__ int dot4(unsigned a, unsigned b, int c) {
#if defined(__has_builtin)
#if __has_builtin(__builtin_amdgcn_sdot4)
  return __builtin_amdgcn_sdot4((int)a, (int)b, c, false);
#else
  return dot4u(a, b, c);
#endif
#else
  return dot4u(a, b, c);
#endif
}

// ---------------------------------------------------------------------------
// K0+K1 merged: bx < 1568 -> quant_x_t tile; else prep_all work
// (BN fold / weight split / kvg zero). No data dependence between branches;
// branch is uniform per block so the quant branch's __syncthreads is safe.
// ---------------------------------------------------------------------------
__global__ __launch_bounds__(256) void prep_quant(
    const float* __restrict__ x, unsigned short* __restrict__ xsb,
    const float* __restrict__ qbn, const float* __restrict__ kbn,
    const float* __restrict__ vbn, const float* __restrict__ pbn,
    const float* __restrict__ qw, const float* __restrict__ kw,
    const float* __restrict__ vw, const float* __restrict__ pw,
    float* __restrict__ bnw, unsigned short* __restrict__ wsp,
    int* __restrict__ kvg) {
  __shared__ unsigned short s[64 * 68];
  const int t = threadIdx.x;
  const int bxg = blockIdx.x;
  if (bxg < 1568) {
    // ---- quant branch: x -> spikes (bf16) in blocked B-fragment layout ----
    const int n0 = (bxg % 49) * 64;
    const int tb = bxg / 49;
    const float* X = x + (size_t)tb * TBC;
    const int nl = t & 63, cq = t >> 6;
    const int c16 = t >> 4, p4 = (t & 15) * 4;
    unsigned short* dstb = xsb + (size_t)tb * XSB_TB;
    for (int cb = 0; cb < 4; ++cb) {
      int cbase = cb * 64;
#pragma unroll
      for (int i = 0; i < 4; ++i) {
        int c = i * 16 + c16;
        float4 v = *(const float4*)&X[(size_t)(cbase + c) * N_ + n0 + p4];
        unsigned short r0 = (unsigned short)(__float_as_uint(fminf(fmaxf(rintf(v.x), 0.f), 8.f)) >> 16);
        unsigned short r1 = (unsigned short)(__float_as_uint(fminf(fmaxf(rintf(v.y), 0.f), 8.f)) >> 16);
        unsigned short r2 = (unsigned short)(__float_as_uint(fminf(fmaxf(rintf(v.z), 0.f), 8.f)) >> 16);
        unsigned short r3 = (unsigned short)(__float_as_uint(fminf(fmaxf(rintf(v.w), 0.f), 8.f)) >> 16);
        uint2 pk2;
        pk2.x = (unsigned)r0 | ((unsigned)r1 << 16);
        pk2.y = (unsigned)r2 | ((unsigned)r3 << 16);
        *(uint2*)&s[c * 68 + p4] = pk2;
      }
      __syncthreads();
#pragma unroll 2
      for (int j = 0; j < 2; ++j) {
        int ccl = j * 4 + cq;
        int cc = cb * 8 + ccl;
        unsigned short v8[8];
#pragma unroll
        for (int d = 0; d < 8; ++d) v8[d] = s[(ccl * 8 + d) * 68 + nl];
        int n = n0 + nl;
        uint4 pk;
        pk.x = (unsigned)v8[0] | ((unsigned)v8[1] << 16);
        pk.y = (unsigned)v8[2] | ((unsigned)v8[3] << 16);
        pk.z = (unsigned)v8[4] | ((unsigned)v8[5] << 16);
        pk.w = (unsigned)v8[6] | ((unsigned)v8[7] << 16);
        *(uint4*)&dstb[(size_t)(n >> 4) * 4096 + cc * 128 + (n & 15) * 8] = pk;
      }
      __syncthreads();
    }
    return;
  }
  // ---- prep branch ----
  const int bx = bxg - 1568;
  if (bx == 0) {
    const float* ps[4] = {qbn, kbn, vbn, pbn};
#pragma unroll
    for (int i = 0; i < 4; ++i) {
      const float* p = ps[i];
      float g = p[t], be = p[256 + t], mn = p[512 + t], vr = p[768 + t];
      float sc = g / sqrtf(vr + 1e-5f);
      float b = __fsub_rn(be, __fmul_rn(mn, sc));
      bnw[i * 512 + t] = sc;
      bnw[i * 512 + 256 + t] = b;
    }
  } else if (bx <= 1024) {
    const float* Ws[4] = {qw, kw, vw, pw};
    int id = bx - 1, co = id & 255, m = id >> 8;
    float w = Ws[m][co * 256 + t];
    float h1, h2, h3r;
    unsigned short u1 = bf16rn(w, &h1);
    float r1 = __fsub_rn(w, h1);
    unsigned short u2 = bf16rn(r1, &h2);
    float r2 = __fsub_rn(r1, h2);
    unsigned short u3 = bf16rn(r2, &h3r);   // exact: r2 has <=8 significant bits
    int rt = co >> 7, ks = t >> 5;
    int lane = (co & 15) + 16 * ((t >> 3) & 3);
    unsigned short us[3] = {u1, u2, u3};
#pragma unroll
    for (int sp = 0; sp < 3; ++sp) {
      size_t off = (size_t)((((m * 3 + sp) * 2 + rt) * 8 + ks)) * 4096 + lane * 8 + (t & 7);
      wsp[off] = us[sp];
    }
  } else {
    int tb = bx - 1025;
    int4* p = (int4*)(kvg + (size_t)tb * 8192);
    for (int i = t; i < 2048; i += 256) p[i] = make_int4(0, 0, 0, 0);
  }
}

// ---------------------------------------------------------------------------
// K2: fused q/k/v GEMM. Proven round-6/8 form (124.9us, MfmaUtil ~40,
// VGPR 84, 3 blocks/CU): 3-slot ring (48KB), distance-2 prefetch, counted
// s_waitcnt vmcnt(4), raw s_barrier. LDS-BW-bound at ~85-90% of the 256B/cy
// pipe (zero bank conflicts) — schedule-space exhausted at this tile.
// ---------------------------------------------------------------------------
__global__ __launch_bounds__(256) void qkv_mfma_sw(
    const unsigned short* __restrict__ xsb, const unsigned short* __restrict__ wsp,
    const float* __restrict__ bnw,
    uint8_t* __restrict__ qsb, uint8_t* __restrict__ ks_, uint8_t* __restrict__ vs) {
  __shared__ __align__(16) char smem[49152];   // ring: 3 x (8KB A + 8KB B)
  const int t = threadIdx.x;
  const int L = t & 63, w = t >> 6;
  const int wrow = w >> 1, wcol = w & 1;
  const int b = blockIdx.x;
  const int oct = b / 48, rem = b % 48;
  const int s = rem >> 3, gl = rem & 7;
  const int g = oct * 8 + gl;
  const int ntile = g % 25, tb = g / 25;
  const int conv = s >> 1, rt = s & 1;
  const int n0 = ntile * 128;

  const char* Bb = (const char*)(xsb + (size_t)tb * XSB_TB) + (size_t)ntile * 65536;
  const char* Ab = (const char*)wsp + ((size_t)(conv * 3) * 16 + rt * 8) * 8192;

  f32x4 acc[4][4];
#pragma unroll
  for (int i = 0; i < 4; ++i)
#pragma unroll
    for (int j = 0; j < 4; ++j) acc[i][j] = (f32x4){0.f, 0.f, 0.f, 0.f};

  // prologue: stage step 0 -> slot 0, step 1 -> slot 1
  glds16(Ab + t * 16, smem + t * 16);
  glds16(Ab + t * 16 + 4096, smem + t * 16 + 4096);
  glds16(Bb + (size_t)w * 8192 + L * 16, smem + 8192 + t * 16);
  glds16(Bb + (size_t)(w + 4) * 8192 + L * 16, smem + 8192 + t * 16 + 4096);
  {
    char* slot1 = smem + 16384;
    const char* Ak1 = Ab + 8192;          // (sp=0, ks=1)
    glds16(Ak1 + t * 16, slot1 + t * 16);
    glds16(Ak1 + t * 16 + 4096, slot1 + t * 16 + 4096);
    const char* Bk1 = Bb + 1024;
    glds16(Bk1 + (size_t)w * 8192 + L * 16, slot1 + 8192 + t * 16);
    glds16(Bk1 + (size_t)(w + 4) * 8192 + L * 16, slot1 + 8192 + t * 16 + 4096);
  }

  // step st: sp = st>>3, ks = st&7  (24 steps)
#pragma unroll 1
  for (int st = 0; st < 24; ++st) {
    if (st < 23) {
      // outstanding here: stage(st+1) only (4 ops) -> retires stage(st)
      asm volatile("s_waitcnt vmcnt(4)" ::: "memory");
    } else {
      asm volatile("s_waitcnt vmcnt(0)" ::: "memory");
    }
    __builtin_amdgcn_s_barrier();
    const int s2 = st + 2;
    if (s2 < 24) {
      char* slotn = smem + (s2 % 3) * 16384;
      const char* Ak = Ab + (size_t)(((s2 >> 3) * 16) + (s2 & 7)) * 8192;
      glds16(Ak + t * 16, slotn + t * 16);
      glds16(Ak + t * 16 + 4096, slotn + t * 16 + 4096);
      const char* Bk = Bb + (size_t)(s2 & 7) * 1024;
      glds16(Bk + (size_t)w * 8192 + L * 16, slotn + 8192 + t * 16);
      glds16(Bk + (size_t)(w + 4) * 8192 + L * 16, slotn + 8192 + t * 16 + 4096);
    }
    char* slotc = smem + (st % 3) * 16384;
    bf16x8 af[4], bfr[4];
#pragma unroll
    for (int i = 0; i < 4; ++i) {
      af[i] = *(const bf16x8*)(slotc + (wrow * 4 + i) * 1024 + L * 16);
      bfr[i] = *(const bf16x8*)(slotc + 8192 + (wcol * 4 + i) * 1024 + L * 16);
    }
#pragma unroll
    for (int i = 0; i < 4; ++i)
#pragma unroll
      for (int j = 0; j < 4; ++j)
        acc[i][j] = __builtin_amdgcn_mfma_f32_16x16x32_bf16(af[i], bfr[j], acc[i][j], 0, 0, 0);
  }

  const float* sbn = bnw + conv * 512;
  const int rbase = rt * 128;
  if (conv == 0) {
    uint8_t* qtb = qsb + (size_t)tb * XSB_TB;   // u8 blocked, same group layout
#pragma unroll
    for (int i = 0; i < 4; ++i) {
      int co0 = rbase + wrow * 64 + i * 16 + ((L >> 4) << 2);
      float s0 = sbn[co0], b0 = sbn[256 + co0];
      float s1 = sbn[co0 + 1], b1 = sbn[256 + co0 + 1];
      float s2v = sbn[co0 + 2], b2 = sbn[256 + co0 + 2];
      float s3 = sbn[co0 + 3], b3 = sbn[256 + co0 + 3];
#pragma unroll
      for (int j = 0; j < 4; ++j) {
        int n = n0 + wcol * 64 + j * 16 + (L & 15);
        if (n < N_) {
          float ss[4] = {s0, s1, s2v, s3}, bb[4] = {b0, b1, b2, b3};
          unsigned wb = 0;
#pragma unroll
          for (int r = 0; r < 4; ++r) {
            float y = acc[i][j][r] * 0.125f;
            float tt = __fadd_rn(__fmul_rn(y, ss[r]), bb[r]);
            float rr = fminf(fmaxf(rintf(tt), 0.f), 8.f);
            wb |= ((unsigned)(uint8_t)rr) << (8 * r);
          }
          *(unsigned*)&qtb[(size_t)(n >> 4) * 4096 + (co0 >> 3) * 128 + (n & 15) * 8 + (co0 & 7)] = wb;
        }
      }
    }
  } else {
    uint8_t* outp = (conv == 1 ? ks_ : vs) + (size_t)tb * TBC;
#pragma unroll
    for (int i = 0; i < 4; ++i) {
      int co0 = rbase + wrow * 64 + i * 16 + ((L >> 4) << 2);
#pragma unroll
      for (int j = 0; j < 4; ++j) {
        int n = n0 + wcol * 64 + j * 16 + (L & 15);
        if (n < N_) {
#pragma unroll
          for (int r = 0; r < 4; ++r) {
            int co = co0 + r;
            float y = acc[i][j][r] * 0.125f;
            float tt = __fadd_rn(__fmul_rn(y, sbn[co]), sbn[256 + co]);
            float rr = fminf(fmaxf(rintf(tt), 0.f), 8.f);
            outp[(size_t)co * N_ + n] = (uint8_t)rr;
          }
        }
      }
    }
  }
}

// ---------------------------------------------------------------------------
// K3: partial kv = k^T v, exact i32 atomics. sv XOR swizzle (verified):
// v-read conflict 4-way -> 2-way. grid (8,32,PARTS)
// ---------------------------------------------------------------------------
__global__ __launch_bounds__(256) void attn_kv(
    const uint8_t* __restrict__ ks, const uint8_t* __restrict__ vs,
    int* __restrict__ kvg) {
  const int h = blockIdx.x, tb = blockIdx.y, part = blockIdx.z;
  const int tid = threadIdx.x;
  __shared__ unsigned sk[32][68];
  __shared__ unsigned sv[32][68];
  const uint8_t* K = ks + (size_t)tb * TBC + h * 32 * N_;
  const uint8_t* V = vs + (size_t)tb * TBC + h * 32 * N_;
  const int d0 = (tid >> 4) * 2;
  const int e0 = (tid & 15) * 2;
  const int vsw = ((e0 >> 1) & 7) << 2;   // read-side XOR for rows e0, e0+1
  const int pbase = part * CHUNK;
  const int pend = pbase + CHUNK;
  int acc[2][2] = {};

  for (int nt = 0; nt < 2; ++nt) {
    int n0 = pbase + nt * 256;
    if (n0 >= pend) break;
    if (nt) __syncthreads();
#pragma unroll
    for (int i = 0; i < 8; ++i) {
      int idx = tid + i * 256;
      int d = idx >> 6, w2 = idx & 63;
      int n = n0 + w2 * 4;
      unsigned kw_ = 0, vw_ = 0;
      if (n < pend) {
        kw_ = *(const unsigned*)&K[d * N_ + n];
        vw_ = *(const unsigned*)&V[d * N_ + n];
      }
      sk[d][w2] = kw_;
      sv[d][w2 ^ (((d >> 1) & 7) << 2)] = vw_;
    }
    __syncthreads();
#pragma unroll
    for (int w2 = 0; w2 < 64; w2 += 4) {
      uint4 ka = *(const uint4*)&sk[d0][w2];
      uint4 kb = *(const uint4*)&sk[d0 + 1][w2];
      uint4 va = *(const uint4*)&sv[e0][w2 ^ vsw];
      uint4 vb = *(const uint4*)&sv[e0 + 1][w2 ^ vsw];
      unsigned kwds[2][4] = {{ka.x, ka.y, ka.z, ka.w}, {kb.x, kb.y, kb.z, kb.w}};
      unsigned vwds[2][4] = {{va.x, va.y, va.z, va.w}, {vb.x, vb.y, vb.z, vb.w}};
#pragma unroll
      for (int di = 0; di < 2; ++di)
#pragma unroll
        for (int ej = 0; ej < 2; ++ej)
#pragma unroll
          for (int c = 0; c < 4; ++c)
            acc[di][ej] = dot4(kwds[di][c], vwds[ej][c], acc[di][ej]);
    }
  }
  int* dst = kvg + ((size_t)(tb * 8 + h)) * 1024;
  atomicAdd(&dst[d0 * 32 + e0], acc[0][0]);
  atomicAdd(&dst[d0 * 32 + e0 + 1], acc[0][1]);
  atomicAdd(&dst[(d0 + 1) * 32 + e0], acc[1][0]);
  atomicAdd(&dst[(d0 + 1) * 32 + e0 + 1], acc[1][1]);
}

// ---------------------------------------------------------------------------
// K3b: split kv ints (< 2^18, nonneg) into 3 truncation-exact bf16 parts,
// laid out as MFMA A-fragment images. 256 blocks (widened).
// ---------------------------------------------------------------------------
__global__ __launch_bounds__(256) void kv_finish(const int* __restrict__ kvg,
                                                 unsigned short* __restrict__ kvimg) {
  const int bx = blockIdx.x, t = threadIdx.x;
  const int tb = bx >> 3;
  const int base = (bx & 7) * 1024;
  const int* src = kvg + (size_t)tb * 8192;
  unsigned short* dst = kvimg + (size_t)tb * 24576;
#pragma unroll
  for (int i = 0; i < 4; ++i) {
    int idx = base + t + i * 256;
    int h = idx >> 10, rem = idx & 1023, d = rem >> 5, e = rem & 31;
    int v = src[idx];
    int b1 = (v > 0) ? (32 - __clz(v)) : 0;
    int sh1 = b1 > 8 ? b1 - 8 : 0;
    int hi = (v >> sh1) << sh1;
    int r1 = v - hi;
    int b2 = (r1 > 0) ? (32 - __clz(r1)) : 0;
    int sh2 = b2 > 8 ? b2 - 8 : 0;
    int mid = (r1 >> sh2) << sh2;
    int r2 = r1 - mid;
    int parts[3] = {hi, mid, r2};
    int mtile = e >> 4, lane = (e & 15) + 16 * (d >> 3), j = d & 7;
#pragma unroll
    for (int sp = 0; sp < 3; ++sp) {
      float f = (float)parts[sp];   // exact: <=8 significant bits
      dst[(size_t)h * 3072 + (sp * 2 + mtile) * 512 + lane * 8 + j] =
          (unsigned short)(__float_as_uint(f) >> 16);
    }
  }
}

// ---------------------------------------------------------------------------
// K3c: o = quant(q . kv * scale) via bf16 MFMA. Double-buffered head
// pipeline (1 barrier/head, T14 issue-early/write-late). grid 800.
// ---------------------------------------------------------------------------
__global__ __launch_bounds__(256) void attn_o_mfma(
    const uint8_t* __restrict__ qsb, const unsigned short* __restrict__ kvimg,
    unsigned short* __restrict__ osb) {
  __shared__ __align__(16) char smem[28672];   // 2 x (8KB B-image + 6KB A-images)
  const int t = threadIdx.x;
  const int L = t & 63, wv = t >> 6;
  const int b = blockIdx.x;
  const int ntile = b % 25, tb = b / 25;
  const uint8_t* Q = qsb + (size_t)tb * XSB_TB + (size_t)ntile * 8 * 4096;
  const unsigned short* KV = kvimg + (size_t)tb * 24576;
  unsigned short* osb_tb = osb + (size_t)tb * XSB_TB;
  const float cscale = (float)(0.3535533905932738 / 512.0);

  // stage(0) fully (loads + writes) into buffer 0
  {
    char* smB = smem;
    char* smA = smem + 8192;
    const char* Ah = (const char*)KV;
    glds16(Ah + t * 16, smA + t * 16);
    if (t < 128) glds16(Ah + 4096 + t * 16, smA + 4096 + t * 16);
#pragma unroll
    for (int it = 0; it < 4; ++it) {
      int w2 = t + it * 256;
      int gl2 = w2 >> 7, wl = w2 & 127, ccp = wl >> 5;
      int rem = (w2 * 4) & 127, n16 = rem >> 3, k7b = rem & 7;
      unsigned wd = *(const unsigned*)&Q[(size_t)gl2 * 4096 + (0 * 4 + ccp) * 128 + n16 * 8 + k7b];
      unsigned short* ds = (unsigned short*)smB + gl2 * 512 + (ccp * 16 + n16) * 8 + k7b;
      float f0 = (float)(wd & 255u), f1 = (float)((wd >> 8) & 255u);
      float f2 = (float)((wd >> 16) & 255u), f3 = (float)(wd >> 24);
      uint2 pk;
      pk.x = (__float_as_uint(f0) >> 16) | ((__float_as_uint(f1) >> 16) << 16);
      pk.y = (__float_as_uint(f2) >> 16) | ((__float_as_uint(f3) >> 16) << 16);
      *(uint2*)ds = pk;
    }
  }

#pragma unroll 1
  for (int h = 0; h < 8; ++h) {
    __syncthreads();   // drains stage(h) glds16 + ds_writes; guards buffer reuse
    char* cur = smem + (h & 1) * 14336;
    char* smB = cur;
    char* smA = cur + 8192;
    // read B frags of head h
    bf16x8 bfr[2];
#pragma unroll
    for (int jj = 0; jj < 2; ++jj)
      bfr[jj] = *(const bf16x8*)(smB + (wv * 2 + jj) * 1024 + L * 16);
    // T14 issue-early: A-images(h+1) via glds16; Q words(h+1) into regs
    unsigned wd[4];
    if (h < 7) {
      char* alt = smem + ((h + 1) & 1) * 14336;
      const char* Ah = (const char*)(KV + (size_t)(h + 1) * 3072);
      glds16(Ah + t * 16, alt + 8192 + t * 16);
      if (t < 128) glds16(Ah + 4096 + t * 16, alt + 8192 + 4096 + t * 16);
#pragma unroll
      for (int it = 0; it < 4; ++it) {
        int w2 = t + it * 256;
        int gl2 = w2 >> 7, wl = w2 & 127, ccp = wl >> 5;
        int rem = (w2 * 4) & 127, n16 = rem >> 3, k7b = rem & 7;
        wd[it] = *(const unsigned*)&Q[(size_t)gl2 * 4096 + ((h + 1) * 4 + ccp) * 128 + n16 * 8 + k7b];
      }
    }
    // MFMAs of head h
    f32x4 acc[2][2];
#pragma unroll
    for (int i = 0; i < 2; ++i)
#pragma unroll
      for (int jj = 0; jj < 2; ++jj) acc[i][jj] = (f32x4){0.f, 0.f, 0.f, 0.f};
#pragma unroll
    for (int sp = 0; sp < 3; ++sp) {
      bf16x8 a0 = *(const bf16x8*)(smA + (sp * 2 + 0) * 1024 + L * 16);
      bf16x8 a1 = *(const bf16x8*)(smA + (sp * 2 + 1) * 1024 + L * 16);
#pragma unroll
      for (int jj = 0; jj < 2; ++jj) {
        acc[0][jj] = __builtin_amdgcn_mfma_f32_16x16x32_bf16(a0, bfr[jj], acc[0][jj], 0, 0, 0);
        acc[1][jj] = __builtin_amdgcn_mfma_f32_16x16x32_bf16(a1, bfr[jj], acc[1][jj], 0, 0, 0);
      }
    }
    // T14 write-late: unpack Q(h+1) -> alt B-image
    if (h < 7) {
      char* alt = smem + ((h + 1) & 1) * 14336;
#pragma unroll
      for (int it = 0; it < 4; ++it) {
        int w2 = t + it * 256;
        int gl2 = w2 >> 7, wl = w2 & 127, ccp = wl >> 5;
        int rem = (w2 * 4) & 127, n16 = rem >> 3, k7b = rem & 7;
        unsigned short* ds = (unsigned short*)alt + gl2 * 512 + (ccp * 16 + n16) * 8 + k7b;
        float f0 = (float)(wd[it] & 255u), f1 = (float)((wd[it] >> 8) & 255u);
        float f2 = (float)((wd[it] >> 16) & 255u), f3 = (float)(wd[it] >> 24);
        uint2 pk;
        pk.x = (__float_as_uint(f0) >> 16) | ((__float_as_uint(f1) >> 16) << 16);
        pk.y = (__float_as_uint(f2) >> 16) | ((__float_as_uint(f3) >> 16) << 16);
        *(uint2*)ds = pk;
      }
    }
    // epilogue of head h
#pragma unroll
    for (int i = 0; i < 2; ++i) {
      int c0 = h * 32 + i * 16 + ((L >> 4) << 2);
#pragma unroll
      for (int jj = 0; jj < 2; ++jj) {
        int n = ntile * 128 + (wv * 2 + jj) * 16 + (L & 15);
        if (n < N_) {
          unsigned short u[4];
#pragma unroll
          for (int r = 0; r < 4; ++r) {
            float of = acc[i][jj][r] * cscale;
            float rr = fminf(fmaxf(rintf(of), 0.f), 8.f);
            u[r] = (unsigned short)(__float_as_uint(rr) >> 16);
          }
          uint2 pk;
          pk.x = (unsigned)u[0] | ((unsigned)u[1] << 16);
          pk.y = (unsigned)u[2] | ((unsigned)u[3] << 16);
          *(uint2*)&osb_tb[(size_t)(n >> 4) * 4096 + (c0 >> 3) * 128 + (n & 15) * 8 + (c0 & 7)] = pk;
        }
      }
    }
  }
}

// ---------------------------------------------------------------------------
// K4: out = BN(pw @ os/8) via bf16 MFMA, 2 splits. Proven round-6/8 form
// (distance-2, 3-slot ring, vmcnt(4), 16 steps).
// ---------------------------------------------------------------------------
__global__ __launch_bounds__(256) void out_mfma_sw(
    const unsigned short* __restrict__ osb, const unsigned short* __restrict__ wsp,
    const float* __restrict__ bnw, float* __restrict__ out) {
  __shared__ __align__(16) char smem[49152];   // ring: 3 x (8KB A + 8KB B)
  const int t = threadIdx.x;
  const int L = t & 63, w = t >> 6;
  const int wrow = w >> 1, wcol = w & 1;
  const int b = blockIdx.x;
  const int oct = b / 16, rem = b % 16;
  const int rt = rem >> 3, gl = rem & 7;
  const int g = oct * 8 + gl;
  const int ntile = g % 25, tb = g / 25;
  const int n0 = ntile * 128;
  const char* Bb = (const char*)(osb + (size_t)tb * XSB_TB) + (size_t)ntile * 65536;
  const char* Ab = (const char*)wsp + ((size_t)9 * 16 + rt * 8) * 8192;

  f32x4 acc[4][4];
#pragma unroll
  for (int i = 0; i < 4; ++i)
#pragma unroll
    for (int j = 0; j < 4; ++j) acc[i][j] = (f32x4){0.f, 0.f, 0.f, 0.f};

  // prologue: stage step 0 -> slot 0, step 1 -> slot 1
  glds16(Ab + t * 16, smem + t * 16);
  glds16(Ab + t * 16 + 4096, smem + t * 16 + 4096);
  glds16(Bb + (size_t)w * 8192 + L * 16, smem + 8192 + t * 16);
  glds16(Bb + (size_t)(w + 4) * 8192 + L * 16, smem + 8192 + t * 16 + 4096);
  {
    char* slot1 = smem + 16384;
    const char* Ak1 = Ab + 8192;          // (sp=0, ks=1)
    glds16(Ak1 + t * 16, slot1 + t * 16);
    glds16(Ak1 + t * 16 + 4096, slot1 + t * 16 + 4096);
    const char* Bk1 = Bb + 1024;
    glds16(Bk1 + (size_t)w * 8192 + L * 16, slot1 + 8192 + t * 16);
    glds16(Bk1 + (size_t)(w + 4) * 8192 + L * 16, slot1 + 8192 + t * 16 + 4096);
  }

  // step st: sp = st>>3, ks = st&7  (16 steps)
#pragma unroll 1
  for (int st = 0; st < 16; ++st) {
    if (st < 15) {
      asm volatile("s_waitcnt vmcnt(4)" ::: "memory");
    } else {
      asm volatile("s_waitcnt vmcnt(0)" ::: "memory");
    }
    __builtin_amdgcn_s_barrier();
    const int s2 = st + 2;
    if (s2 < 16) {
      char* slotn = smem + (s2 % 3) * 16384;
      const char* Ak = Ab + (size_t)(((s2 >> 3) * 16) + (s2 & 7)) * 8192;
      glds16(Ak + t * 16, slotn + t * 16);
      glds16(Ak + t * 16 + 4096, slotn + t * 16 + 4096);
      const char* Bk = Bb + (size_t)(s2 & 7) * 1024;
      glds16(Bk + (size_t)w * 8192 + L * 16, slotn + 8192 + t * 16);
      glds16(Bk + (size_t)(w + 4) * 8192 + L * 16, slotn + 8192 + t * 16 + 4096);
    }
    char* slotc = smem + (st % 3) * 16384;
    bf16x8 af[4], bfr[4];
#pragma unroll
    for (int i = 0; i < 4; ++i) {
      af[i] = *(const bf16x8*)(slotc + (wrow * 4 + i) * 1024 + L * 16);
      bfr[i] = *(const bf16x8*)(slotc + 8192 + (wcol * 4 + i) * 1024 + L * 16);
    }
#pragma unroll
    for (int i = 0; i < 4; ++i)
#pragma unroll
      for (int j = 0; j < 4; ++j)
        acc[i][j] = __builtin_amdgcn_mfma_f32_16x16x32_bf16(af[i], bfr[j], acc[i][j], 0, 0, 0);
  }

  float* O = out + (size_t)tb * TBC;
  const float* sbn = bnw + 3 * 512;
  const int rbase = rt * 128;
#pragma unroll
  for (int i = 0; i < 4; ++i) {
    int co0 = rbase + wrow * 64 + i * 16 + ((L >> 4) << 2);
#pragma unroll
    for (int j = 0; j < 4; ++j) {
      int n = n0 + wcol * 64 + j * 16 + (L & 15);
      if (n < N_) {
#pragma unroll
        for (int r = 0; r < 4; ++r) {
          int co = co0 + r;
          float y = acc[i][j][r] * 0.125f;
          O[(size_t)co * N_ + n] = __fadd_rn(__fmul_rn(y, sbn[co]), sbn[256 + co]);
        }
      }
    }
  }
}

// ---------------------------------------------------------------------------
extern "C" void kernel_launch(void* const* d_in, const int* in_sizes, int n_in,
                              void* d_out, int out_size, void* d_ws, size_t ws_size,
                              hipStream_t stream) {
  const float* x   = (const float*)d_in[0];
  const float* qw  = (const float*)d_in[1];
  const float* qbn = (const float*)d_in[2];
  const float* kw  = (const float*)d_in[3];
  const float* kbn = (const float*)d_in[4];
  const float* vw  = (const float*)d_in[5];
  const float* vbn = (const float*)d_in[6];
  const float* pw  = (const float*)d_in[7];
  const float* pbn = (const float*)d_in[8];
  float* out = (float*)d_out;

  uint8_t* ws = (uint8_t*)d_ws;
  float* bnw           = (float*)ws;                           // 8 KB
  unsigned short* wsp  = (unsigned short*)(ws + 8192);         // 1.57 MB
  unsigned short* xsb  = (unsigned short*)(ws + 1581056);      // 52.43 MB
  uint8_t* qsb         = ws + 54009856;                        // 26.21 MB u8 blocked q
  uint8_t* ksp         = ws + 80224256;                        // 25.69 MB
  uint8_t* vsp         = ws + 105914368;                       // 25.69 MB
  int* kvg             = (int*)(ws + 131604480);               // 1.05 MB
  unsigned short* kvimg = (unsigned short*)(ws + 132653056);   // 1.57 MB -> ends 134.2 MB
  unsigned short* osb  = xsb;   // alias: xsb dead after qkv

  prep_quant<<<2625, 256, 0, stream>>>(x, xsb, qbn, kbn, vbn, pbn,
                                       qw, kw, vw, pw, bnw, wsp, kvg);
  qkv_mfma_sw<<<4800, 256, 0, stream>>>(xsb, wsp, bnw, qsb, ksp, vsp);
  attn_kv<<<dim3(8, 32, PARTS), 256, 0, stream>>>(ksp, vsp, kvg);
  kv_finish<<<256, 256, 0, stream>>>(kvg, kvimg);
  attn_o_mfma<<<800, 256, 0, stream>>>(qsb, kvimg, osb);
  out_mfma_sw<<<1600, 256, 0, stream>>>(osb, wsp, bnw, out);
}

// Round 12
// 385.515 us; speedup vs baseline: 1.0458x; 1.0024x over previous
//
#include <hip/hip_runtime.h>
#include <stdint.h>

#define TB_ 32
#define C_ 256
#define N_ 3136
#define TBC (C_ * N_)            // 802816 elems per (t,b) per 256-ch tensor
#define ACT_SZ (TB_ * TBC)       // 25690112
#define XSB_TB 819200            // elems per tb in blocked layouts (200 groups * 4096)
#define PARTS 7
#define CHUNK 448                // 3136/7, multiple of 16

typedef __attribute__((ext_vector_type(8))) short bf16x8;
typedef __attribute__((ext_vector_type(4))) float f32x4;

__device__ __forceinline__ void glds16(const void* gp, void* lp) {
  __builtin_amdgcn_global_load_lds(
      (const __attribute__((address_space(1))) unsigned int*)gp,
      (__attribute__((address_space(3))) unsigned int*)lp, 16, 0, 0);
}

__device__ __forceinline__ unsigned short bf16rn(float f, float* val) {
  unsigned b = __float_as_uint(f);
  unsigned r = (b + 0x7fffu + ((b >> 16) & 1u)) >> 16;
  *val = __uint_as_float(r << 16);
  return (unsigned short)r;
}

__device__ __forceinline__ int dot4u(unsigned a, unsigned b, int c) {
  c += (int)(a & 255u)         * (int)(b & 255u);
  c += (int)((a >> 8) & 255u)  * (int)((b >> 8) & 255u);
  c += (int)((a >> 16) & 255u) * (int)((b >> 16) & 255u);
  c += (int)(a >> 24)          * (int)(b >> 24);
  return c;
}

__device__ __forceinline__ int dot4(unsigned a, unsigned b, int c) {
#if defined(__has_builtin)
#if __has_builtin(__builtin_amdgcn_sdot4)
  return __builtin_amdgcn_sdot4((int)a, (int)b, c, false);
#else
  return dot4u(a, b, c);
#endif
#else
  return dot4u(a, b, c);
#endif
}

// 3-way truncation-exact split of a nonneg int (< 2^18) into bf16 parts,
// written as A-fragment image shorts. Byte-identical math to old kv_finish.
__device__ __forceinline__ void kv_split3(int v, unsigned short us[3]) {
  int b1 = (v > 0) ? (32 - __clz(v)) : 0;
  int sh1 = b1 > 8 ? b1 - 8 : 0;
  int hi = (v >> sh1) << sh1;
  int r1 = v - hi;
  int b2 = (r1 > 0) ? (32 - __clz(r1)) : 0;
  int sh2 = b2 > 8 ? b2 - 8 : 0;
  int mid = (r1 >> sh2) << sh2;
  int r2 = r1 - mid;
  int parts[3] = {hi, mid, r2};
#pragma unroll
  for (int sp = 0; sp < 3; ++sp)
    us[sp] = (unsigned short)(__float_as_uint((float)parts[sp]) >> 16);
}

// ---------------------------------------------------------------------------
// K0+K1 merged: bx < 1568 -> quant_x_t tile; else prep_all work
// (BN fold / weight split / kvg zero). No data dependence between branches;
// branch is uniform per block so the quant branch's __syncthreads is safe.
// ---------------------------------------------------------------------------
__global__ __launch_bounds__(256) void prep_quant(
    const float* __restrict__ x, unsigned short* __restrict__ xsb,
    const float* __restrict__ qbn, const float* __restrict__ kbn,
    const float* __restrict__ vbn, const float* __restrict__ pbn,
    const float* __restrict__ qw, const float* __restrict__ kw,
    const float* __restrict__ vw, const float* __restrict__ pw,
    float* __restrict__ bnw, unsigned short* __restrict__ wsp,
    int* __restrict__ kvg) {
  __shared__ unsigned short s[64 * 68];
  const int t = threadIdx.x;
  const int bxg = blockIdx.x;
  if (bxg < 1568) {
    // ---- quant branch: x -> spikes (bf16) in blocked B-fragment layout ----
    const int n0 = (bxg % 49) * 64;
    const int tb = bxg / 49;
    const float* X = x + (size_t)tb * TBC;
    const int nl = t & 63, cq = t >> 6;
    const int c16 = t >> 4, p4 = (t & 15) * 4;
    unsigned short* dstb = xsb + (size_t)tb * XSB_TB;
    for (int cb = 0; cb < 4; ++cb) {
      int cbase = cb * 64;
#pragma unroll
      for (int i = 0; i < 4; ++i) {
        int c = i * 16 + c16;
        float4 v = *(const float4*)&X[(size_t)(cbase + c) * N_ + n0 + p4];
        unsigned short r0 = (unsigned short)(__float_as_uint(fminf(fmaxf(rintf(v.x), 0.f), 8.f)) >> 16);
        unsigned short r1 = (unsigned short)(__float_as_uint(fminf(fmaxf(rintf(v.y), 0.f), 8.f)) >> 16);
        unsigned short r2 = (unsigned short)(__float_as_uint(fminf(fmaxf(rintf(v.z), 0.f), 8.f)) >> 16);
        unsigned short r3 = (unsigned short)(__float_as_uint(fminf(fmaxf(rintf(v.w), 0.f), 8.f)) >> 16);
        uint2 pk2;
        pk2.x = (unsigned)r0 | ((unsigned)r1 << 16);
        pk2.y = (unsigned)r2 | ((unsigned)r3 << 16);
        *(uint2*)&s[c * 68 + p4] = pk2;
      }
      __syncthreads();
#pragma unroll 2
      for (int j = 0; j < 2; ++j) {
        int ccl = j * 4 + cq;
        int cc = cb * 8 + ccl;
        unsigned short v8[8];
#pragma unroll
        for (int d = 0; d < 8; ++d) v8[d] = s[(ccl * 8 + d) * 68 + nl];
        int n = n0 + nl;
        uint4 pk;
        pk.x = (unsigned)v8[0] | ((unsigned)v8[1] << 16);
        pk.y = (unsigned)v8[2] | ((unsigned)v8[3] << 16);
        pk.z = (unsigned)v8[4] | ((unsigned)v8[5] << 16);
        pk.w = (unsigned)v8[6] | ((unsigned)v8[7] << 16);
        *(uint4*)&dstb[(size_t)(n >> 4) * 4096 + cc * 128 + (n & 15) * 8] = pk;
      }
      __syncthreads();
    }
    return;
  }
  // ---- prep branch ----
  const int bx = bxg - 1568;
  if (bx == 0) {
    const float* ps[4] = {qbn, kbn, vbn, pbn};
#pragma unroll
    for (int i = 0; i < 4; ++i) {
      const float* p = ps[i];
      float g = p[t], be = p[256 + t], mn = p[512 + t], vr = p[768 + t];
      float sc = g / sqrtf(vr + 1e-5f);
      float b = __fsub_rn(be, __fmul_rn(mn, sc));
      bnw[i * 512 + t] = sc;
      bnw[i * 512 + 256 + t] = b;
    }
  } else if (bx <= 1024) {
    const float* Ws[4] = {qw, kw, vw, pw};
    int id = bx - 1, co = id & 255, m = id >> 8;
    float w = Ws[m][co * 256 + t];
    float h1, h2, h3r;
    unsigned short u1 = bf16rn(w, &h1);
    float r1 = __fsub_rn(w, h1);
    unsigned short u2 = bf16rn(r1, &h2);
    float r2 = __fsub_rn(r1, h2);
    unsigned short u3 = bf16rn(r2, &h3r);   // exact: r2 has <=8 significant bits
    int rt = co >> 7, ks = t >> 5;
    int lane = (co & 15) + 16 * ((t >> 3) & 3);
    unsigned short us[3] = {u1, u2, u3};
#pragma unroll
    for (int sp = 0; sp < 3; ++sp) {
      size_t off = (size_t)((((m * 3 + sp) * 2 + rt) * 8 + ks)) * 4096 + lane * 8 + (t & 7);
      wsp[off] = us[sp];
    }
  } else {
    int tb = bx - 1025;
    int4* p = (int4*)(kvg + (size_t)tb * 8192);
    for (int i = t; i < 2048; i += 256) p[i] = make_int4(0, 0, 0, 0);
  }
}

// ---------------------------------------------------------------------------
// K2: fused q/k/v GEMM. Proven round-6/8 form (124.9us, MfmaUtil ~40,
// VGPR 84, 3 blocks/CU): 3-slot ring (48KB), distance-2 prefetch, counted
// s_waitcnt vmcnt(4), raw s_barrier. LDS-BW-bound at ~76% of the measured
// ds_read_b128 pipe (zero bank conflicts) — schedule-space exhausted here.
// ---------------------------------------------------------------------------
__global__ __launch_bounds__(256) void qkv_mfma_sw(
    const unsigned short* __restrict__ xsb, const unsigned short* __restrict__ wsp,
    const float* __restrict__ bnw,
    uint8_t* __restrict__ qsb, uint8_t* __restrict__ ks_, uint8_t* __restrict__ vs) {
  __shared__ __align__(16) char smem[49152];   // ring: 3 x (8KB A + 8KB B)
  const int t = threadIdx.x;
  const int L = t & 63, w = t >> 6;
  const int wrow = w >> 1, wcol = w & 1;
  const int b = blockIdx.x;
  const int oct = b / 48, rem = b % 48;
  const int s = rem >> 3, gl = rem & 7;
  const int g = oct * 8 + gl;
  const int ntile = g % 25, tb = g / 25;
  const int conv = s >> 1, rt = s & 1;
  const int n0 = ntile * 128;

  const char* Bb = (const char*)(xsb + (size_t)tb * XSB_TB) + (size_t)ntile * 65536;
  const char* Ab = (const char*)wsp + ((size_t)(conv * 3) * 16 + rt * 8) * 8192;

  f32x4 acc[4][4];
#pragma unroll
  for (int i = 0; i < 4; ++i)
#pragma unroll
    for (int j = 0; j < 4; ++j) acc[i][j] = (f32x4){0.f, 0.f, 0.f, 0.f};

  // prologue: stage step 0 -> slot 0, step 1 -> slot 1
  glds16(Ab + t * 16, smem + t * 16);
  glds16(Ab + t * 16 + 4096, smem + t * 16 + 4096);
  glds16(Bb + (size_t)w * 8192 + L * 16, smem + 8192 + t * 16);
  glds16(Bb + (size_t)(w + 4) * 8192 + L * 16, smem + 8192 + t * 16 + 4096);
  {
    char* slot1 = smem + 16384;
    const char* Ak1 = Ab + 8192;          // (sp=0, ks=1)
    glds16(Ak1 + t * 16, slot1 + t * 16);
    glds16(Ak1 + t * 16 + 4096, slot1 + t * 16 + 4096);
    const char* Bk1 = Bb + 1024;
    glds16(Bk1 + (size_t)w * 8192 + L * 16, slot1 + 8192 + t * 16);
    glds16(Bk1 + (size_t)(w + 4) * 8192 + L * 16, slot1 + 8192 + t * 16 + 4096);
  }

  // step st: sp = st>>3, ks = st&7  (24 steps)
#pragma unroll 1
  for (int st = 0; st < 24; ++st) {
    if (st < 23) {
      // outstanding here: stage(st+1) only (4 ops) -> retires stage(st)
      asm volatile("s_waitcnt vmcnt(4)" ::: "memory");
    } else {
      asm volatile("s_waitcnt vmcnt(0)" ::: "memory");
    }
    __builtin_amdgcn_s_barrier();
    const int s2 = st + 2;
    if (s2 < 24) {
      char* slotn = smem + (s2 % 3) * 16384;
      const char* Ak = Ab + (size_t)(((s2 >> 3) * 16) + (s2 & 7)) * 8192;
      glds16(Ak + t * 16, slotn + t * 16);
      glds16(Ak + t * 16 + 4096, slotn + t * 16 + 4096);
      const char* Bk = Bb + (size_t)(s2 & 7) * 1024;
      glds16(Bk + (size_t)w * 8192 + L * 16, slotn + 8192 + t * 16);
      glds16(Bk + (size_t)(w + 4) * 8192 + L * 16, slotn + 8192 + t * 16 + 4096);
    }
    char* slotc = smem + (st % 3) * 16384;
    bf16x8 af[4], bfr[4];
#pragma unroll
    for (int i = 0; i < 4; ++i) {
      af[i] = *(const bf16x8*)(slotc + (wrow * 4 + i) * 1024 + L * 16);
      bfr[i] = *(const bf16x8*)(slotc + 8192 + (wcol * 4 + i) * 1024 + L * 16);
    }
#pragma unroll
    for (int i = 0; i < 4; ++i)
#pragma unroll
      for (int j = 0; j < 4; ++j)
        acc[i][j] = __builtin_amdgcn_mfma_f32_16x16x32_bf16(af[i], bfr[j], acc[i][j], 0, 0, 0);
  }

  const float* sbn = bnw + conv * 512;
  const int rbase = rt * 128;
  if (conv == 0) {
    uint8_t* qtb = qsb + (size_t)tb * XSB_TB;   // u8 blocked, same group layout
#pragma unroll
    for (int i = 0; i < 4; ++i) {
      int co0 = rbase + wrow * 64 + i * 16 + ((L >> 4) << 2);
      float s0 = sbn[co0], b0 = sbn[256 + co0];
      float s1 = sbn[co0 + 1], b1 = sbn[256 + co0 + 1];
      float s2v = sbn[co0 + 2], b2 = sbn[256 + co0 + 2];
      float s3 = sbn[co0 + 3], b3 = sbn[256 + co0 + 3];
#pragma unroll
      for (int j = 0; j < 4; ++j) {
        int n = n0 + wcol * 64 + j * 16 + (L & 15);
        if (n < N_) {
          float ss[4] = {s0, s1, s2v, s3}, bb[4] = {b0, b1, b2, b3};
          unsigned wb = 0;
#pragma unroll
          for (int r = 0; r < 4; ++r) {
            float y = acc[i][j][r] * 0.125f;
            float tt = __fadd_rn(__fmul_rn(y, ss[r]), bb[r]);
            float rr = fminf(fmaxf(rintf(tt), 0.f), 8.f);
            wb |= ((unsigned)(uint8_t)rr) << (8 * r);
          }
          *(unsigned*)&qtb[(size_t)(n >> 4) * 4096 + (co0 >> 3) * 128 + (n & 15) * 8 + (co0 & 7)] = wb;
        }
      }
    }
  } else {
    uint8_t* outp = (conv == 1 ? ks_ : vs) + (size_t)tb * TBC;
#pragma unroll
    for (int i = 0; i < 4; ++i) {
      int co0 = rbase + wrow * 64 + i * 16 + ((L >> 4) << 2);
#pragma unroll
      for (int j = 0; j < 4; ++j) {
        int n = n0 + wcol * 64 + j * 16 + (L & 15);
        if (n < N_) {
#pragma unroll
          for (int r = 0; r < 4; ++r) {
            int co = co0 + r;
            float y = acc[i][j][r] * 0.125f;
            float tt = __fadd_rn(__fmul_rn(y, sbn[co]), sbn[256 + co]);
            float rr = fminf(fmaxf(rintf(tt), 0.f), 8.f);
            outp[(size_t)co * N_ + n] = (uint8_t)rr;
          }
        }
      }
    }
  }
}

// ---------------------------------------------------------------------------
// K3: partial kv = k^T v, exact i32 atomics. sv XOR swizzle (verified):
// v-read conflict 4-way -> 2-way. grid (8,32,PARTS)
// ---------------------------------------------------------------------------
__global__ __launch_bounds__(256) void attn_kv(
    const uint8_t* __restrict__ ks, const uint8_t* __restrict__ vs,
    int* __restrict__ kvg) {
  const int h = blockIdx.x, tb = blockIdx.y, part = blockIdx.z;
  const int tid = threadIdx.x;
  __shared__ unsigned sk[32][68];
  __shared__ unsigned sv[32][68];
  const uint8_t* K = ks + (size_t)tb * TBC + h * 32 * N_;
  const uint8_t* V = vs + (size_t)tb * TBC + h * 32 * N_;
  const int d0 = (tid >> 4) * 2;
  const int e0 = (tid & 15) * 2;
  const int vsw = ((e0 >> 1) & 7) << 2;   // read-side XOR for rows e0, e0+1
  const int pbase = part * CHUNK;
  const int pend = pbase + CHUNK;
  int acc[2][2] = {};

  for (int nt = 0; nt < 2; ++nt) {
    int n0 = pbase + nt * 256;
    if (n0 >= pend) break;
    if (nt) __syncthreads();
#pragma unroll
    for (int i = 0; i < 8; ++i) {
      int idx = tid + i * 256;
      int d = idx >> 6, w2 = idx & 63;
      int n = n0 + w2 * 4;
      unsigned kw_ = 0, vw_ = 0;
      if (n < pend) {
        kw_ = *(const unsigned*)&K[d * N_ + n];
        vw_ = *(const unsigned*)&V[d * N_ + n];
      }
      sk[d][w2] = kw_;
      sv[d][w2 ^ (((d >> 1) & 7) << 2)] = vw_;
    }
    __syncthreads();
#pragma unroll
    for (int w2 = 0; w2 < 64; w2 += 4) {
      uint4 ka = *(const uint4*)&sk[d0][w2];
      uint4 kb = *(const uint4*)&sk[d0 + 1][w2];
      uint4 va = *(const uint4*)&sv[e0][w2 ^ vsw];
      uint4 vb = *(const uint4*)&sv[e0 + 1][w2 ^ vsw];
      unsigned kwds[2][4] = {{ka.x, ka.y, ka.z, ka.w}, {kb.x, kb.y, kb.z, kb.w}};
      unsigned vwds[2][4] = {{va.x, va.y, va.z, va.w}, {vb.x, vb.y, vb.z, vb.w}};
#pragma unroll
      for (int di = 0; di < 2; ++di)
#pragma unroll
        for (int ej = 0; ej < 2; ++ej)
#pragma unroll
          for (int c = 0; c < 4; ++c)
            acc[di][ej] = dot4(kwds[di][c], vwds[ej][c], acc[di][ej]);
    }
  }
  int* dst = kvg + ((size_t)(tb * 8 + h)) * 1024;
  atomicAdd(&dst[d0 * 32 + e0], acc[0][0]);
  atomicAdd(&dst[d0 * 32 + e0 + 1], acc[0][1]);
  atomicAdd(&dst[(d0 + 1) * 32 + e0], acc[1][0]);
  atomicAdd(&dst[(d0 + 1) * 32 + e0 + 1], acc[1][1]);
}

// ---------------------------------------------------------------------------
// K3c: o = quant(q . kv * scale) via bf16 MFMA. Round-12: kv_finish FOLDED
// in — each block converts its tb's kvg head-slice (1024 L2-hot ints,
// 4/thread) to the A-fragment image on the fly, in the T14 slot: kvg loads
// issued BEFORE the MFMAs (with the Q loads), convert+ds_write AFTER.
// Split math byte-identical to old kv_finish -> bitwise-identical output.
// Removes one kernel launch + device drain. LDS 28KB unchanged. grid 800.
// ---------------------------------------------------------------------------
__global__ __launch_bounds__(256) void attn_o_mfma(
    const uint8_t* __restrict__ qsb, const int* __restrict__ kvg,
    unsigned short* __restrict__ osb) {
  __shared__ __align__(16) char smem[28672];   // 2 x (8KB B-image + 6KB A-images)
  const int t = threadIdx.x;
  const int L = t & 63, wv = t >> 6;
  const int b = blockIdx.x;
  const int ntile = b % 25, tb = b / 25;
  const uint8_t* Q = qsb + (size_t)tb * XSB_TB + (size_t)ntile * 8 * 4096;
  const int* KVg = kvg + (size_t)tb * 8192;
  unsigned short* osb_tb = osb + (size_t)tb * XSB_TB;
  const float cscale = (float)(0.3535533905932738 / 512.0);

  // per-thread kv-convert indexing: this thread owns rem = 4t..4t+3 of each
  // head slice (same d for all 4; e = consecutive).
  const int kd = (t * 4) >> 5;          // d = rem>>5
  const int ke0 = (t * 4) & 31;         // first e
  const int kmt = ke0 >> 4;             // mtile (same for all 4: 4|e)
  const int kj = kd & 7;                // j
  const int klane0 = (ke0 & 15) + 16 * (kd >> 3);

  // stage(0) fully into buffer 0: convert kvg head 0 -> A-image; unpack Q(0)
  {
    char* smB = smem;
    unsigned short* smA = (unsigned short*)(smem + 8192);
#pragma unroll
    for (int q = 0; q < 4; ++q) {
      int v = KVg[kd * 32 + ke0 + q];
      unsigned short us[3];
      kv_split3(v, us);
#pragma unroll
      for (int sp = 0; sp < 3; ++sp)
        smA[(sp * 2 + kmt) * 512 + (klane0 + q) * 8 + kj] = us[sp];
    }
#pragma unroll
    for (int it = 0; it < 4; ++it) {
      int w2 = t + it * 256;
      int gl2 = w2 >> 7, wl = w2 & 127, ccp = wl >> 5;
      int rem = (w2 * 4) & 127, n16 = rem >> 3, k7b = rem & 7;
      unsigned wd = *(const unsigned*)&Q[(size_t)gl2 * 4096 + (0 * 4 + ccp) * 128 + n16 * 8 + k7b];
      unsigned short* ds = (unsigned short*)smB + gl2 * 512 + (ccp * 16 + n16) * 8 + k7b;
      float f0 = (float)(wd & 255u), f1 = (float)((wd >> 8) & 255u);
      float f2 = (float)((wd >> 16) & 255u), f3 = (float)(wd >> 24);
      uint2 pk;
      pk.x = (__float_as_uint(f0) >> 16) | ((__float_as_uint(f1) >> 16) << 16);
      pk.y = (__float_as_uint(f2) >> 16) | ((__float_as_uint(f3) >> 16) << 16);
      *(uint2*)ds = pk;
    }
  }

#pragma unroll 1
  for (int h = 0; h < 8; ++h) {
    __syncthreads();   // stage(h) ds_writes visible; guards buffer reuse
    char* cur = smem + (h & 1) * 14336;
    char* smB = cur;
    char* smA = cur + 8192;
    // read B frags of head h
    bf16x8 bfr[2];
#pragma unroll
    for (int jj = 0; jj < 2; ++jj)
      bfr[jj] = *(const bf16x8*)(smB + (wv * 2 + jj) * 1024 + L * 16);
    // T14 issue-early: Q words(h+1) and kvg ints(h+1) into regs
    unsigned wd[4];
    int kvv[4];
    if (h < 7) {
      const int* src = KVg + (h + 1) * 1024;
#pragma unroll
      for (int q = 0; q < 4; ++q) kvv[q] = src[kd * 32 + ke0 + q];
#pragma unroll
      for (int it = 0; it < 4; ++it) {
        int w2 = t + it * 256;
        int gl2 = w2 >> 7, wl = w2 & 127, ccp = wl >> 5;
        int rem = (w2 * 4) & 127, n16 = rem >> 3, k7b = rem & 7;
        wd[it] = *(const unsigned*)&Q[(size_t)gl2 * 4096 + ((h + 1) * 4 + ccp) * 128 + n16 * 8 + k7b];
      }
    }
    // MFMAs of head h
    f32x4 acc[2][2];
#pragma unroll
    for (int i = 0; i < 2; ++i)
#pragma unroll
      for (int jj = 0; jj < 2; ++jj) acc[i][jj] = (f32x4){0.f, 0.f, 0.f, 0.f};
#pragma unroll
    for (int sp = 0; sp < 3; ++sp) {
      bf16x8 a0 = *(const bf16x8*)(smA + (sp * 2 + 0) * 1024 + L * 16);
      bf16x8 a1 = *(const bf16x8*)(smA + (sp * 2 + 1) * 1024 + L * 16);
#pragma unroll
      for (int jj = 0; jj < 2; ++jj) {
        acc[0][jj] = __builtin_amdgcn_mfma_f32_16x16x32_bf16(a0, bfr[jj], acc[0][jj], 0, 0, 0);
        acc[1][jj] = __builtin_amdgcn_mfma_f32_16x16x32_bf16(a1, bfr[jj], acc[1][jj], 0, 0, 0);
      }
    }
    // T14 write-late: unpack Q(h+1) -> alt B-image; convert kv(h+1) -> alt A
    if (h < 7) {
      char* alt = smem + ((h + 1) & 1) * 14336;
      unsigned short* altA = (unsigned short*)(alt + 8192);
#pragma unroll
      for (int q = 0; q < 4; ++q) {
        unsigned short us[3];
        kv_split3(kvv[q], us);
#pragma unroll
        for (int sp = 0; sp < 3; ++sp)
          altA[(sp * 2 + kmt) * 512 + (klane0 + q) * 8 + kj] = us[sp];
      }
#pragma unroll
      for (int it = 0; it < 4; ++it) {
        int w2 = t + it * 256;
        int gl2 = w2 >> 7, wl = w2 & 127, ccp = wl >> 5;
        int rem = (w2 * 4) & 127, n16 = rem >> 3, k7b = rem & 7;
        unsigned short* ds = (unsigned short*)alt + gl2 * 512 + (ccp * 16 + n16) * 8 + k7b;
        float f0 = (float)(wd[it] & 255u), f1 = (float)((wd[it] >> 8) & 255u);
        float f2 = (float)((wd[it] >> 16) & 255u), f3 = (float)(wd[it] >> 24);
        uint2 pk;
        pk.x = (__float_as_uint(f0) >> 16) | ((__float_as_uint(f1) >> 16) << 16);
        pk.y = (__float_as_uint(f2) >> 16) | ((__float_as_uint(f3) >> 16) << 16);
        *(uint2*)ds = pk;
      }
    }
    // epilogue of head h
#pragma unroll
    for (int i = 0; i < 2; ++i) {
      int c0 = h * 32 + i * 16 + ((L >> 4) << 2);
#pragma unroll
      for (int jj = 0; jj < 2; ++jj) {
        int n = ntile * 128 + (wv * 2 + jj) * 16 + (L & 15);
        if (n < N_) {
          unsigned short u[4];
#pragma unroll
          for (int r = 0; r < 4; ++r) {
            float of = acc[i][jj][r] * cscale;
            float rr = fminf(fmaxf(rintf(of), 0.f), 8.f);
            u[r] = (unsigned short)(__float_as_uint(rr) >> 16);
          }
          uint2 pk;
          pk.x = (unsigned)u[0] | ((unsigned)u[1] << 16);
          pk.y = (unsigned)u[2] | ((unsigned)u[3] << 16);
          *(uint2*)&osb_tb[(size_t)(n >> 4) * 4096 + (c0 >> 3) * 128 + (n & 15) * 8 + (c0 & 7)] = pk;
        }
      }
    }
  }
}

// ---------------------------------------------------------------------------
// K4: out = BN(pw @ os/8) via bf16 MFMA, 2 splits. Proven round-6/8 form
// (distance-2, 3-slot ring, vmcnt(4), 16 steps).
// ---------------------------------------------------------------------------
__global__ __launch_bounds__(256) void out_mfma_sw(
    const unsigned short* __restrict__ osb, const unsigned short* __restrict__ wsp,
    const float* __restrict__ bnw, float* __restrict__ out) {
  __shared__ __align__(16) char smem[49152];   // ring: 3 x (8KB A + 8KB B)
  const int t = threadIdx.x;
  const int L = t & 63, w = t >> 6;
  const int wrow = w >> 1, wcol = w & 1;
  const int b = blockIdx.x;
  const int oct = b / 16, rem = b % 16;
  const int rt = rem >> 3, gl = rem & 7;
  const int g = oct * 8 + gl;
  const int ntile = g % 25, tb = g / 25;
  const int n0 = ntile * 128;
  const char* Bb = (const char*)(osb + (size_t)tb * XSB_TB) + (size_t)ntile * 65536;
  const char* Ab = (const char*)wsp + ((size_t)9 * 16 + rt * 8) * 8192;

  f32x4 acc[4][4];
#pragma unroll
  for (int i = 0; i < 4; ++i)
#pragma unroll
    for (int j = 0; j < 4; ++j) acc[i][j] = (f32x4){0.f, 0.f, 0.f, 0.f};

  // prologue: stage step 0 -> slot 0, step 1 -> slot 1
  glds16(Ab + t * 16, smem + t * 16);
  glds16(Ab + t * 16 + 4096, smem + t * 16 + 4096);
  glds16(Bb + (size_t)w * 8192 + L * 16, smem + 8192 + t * 16);
  glds16(Bb + (size_t)(w + 4) * 8192 + L * 16, smem + 8192 + t * 16 + 4096);
  {
    char* slot1 = smem + 16384;
    const char* Ak1 = Ab + 8192;          // (sp=0, ks=1)
    glds16(Ak1 + t * 16, slot1 + t * 16);
    glds16(Ak1 + t * 16 + 4096, slot1 + t * 16 + 4096);
    const char* Bk1 = Bb + 1024;
    glds16(Bk1 + (size_t)w * 8192 + L * 16, slot1 + 8192 + t * 16);
    glds16(Bk1 + (size_t)(w + 4) * 8192 + L * 16, slot1 + 8192 + t * 16 + 4096);
  }

  // step st: sp = st>>3, ks = st&7  (16 steps)
#pragma unroll 1
  for (int st = 0; st < 16; ++st) {
    if (st < 15) {
      asm volatile("s_waitcnt vmcnt(4)" ::: "memory");
    } else {
      asm volatile("s_waitcnt vmcnt(0)" ::: "memory");
    }
    __builtin_amdgcn_s_barrier();
    const int s2 = st + 2;
    if (s2 < 16) {
      char* slotn = smem + (s2 % 3) * 16384;
      const char* Ak = Ab + (size_t)(((s2 >> 3) * 16) + (s2 & 7)) * 8192;
      glds16(Ak + t * 16, slotn + t * 16);
      glds16(Ak + t * 16 + 4096, slotn + t * 16 + 4096);
      const char* Bk = Bb + (size_t)(s2 & 7) * 1024;
      glds16(Bk + (size_t)w * 8192 + L * 16, slotn + 8192 + t * 16);
      glds16(Bk + (size_t)(w + 4) * 8192 + L * 16, slotn + 8192 + t * 16 + 4096);
    }
    char* slotc = smem + (st % 3) * 16384;
    bf16x8 af[4], bfr[4];
#pragma unroll
    for (int i = 0; i < 4; ++i) {
      af[i] = *(const bf16x8*)(slotc + (wrow * 4 + i) * 1024 + L * 16);
      bfr[i] = *(const bf16x8*)(slotc + 8192 + (wcol * 4 + i) * 1024 + L * 16);
    }
#pragma unroll
    for (int i = 0; i < 4; ++i)
#pragma unroll
      for (int j = 0; j < 4; ++j)
        acc[i][j] = __builtin_amdgcn_mfma_f32_16x16x32_bf16(af[i], bfr[j], acc[i][j], 0, 0, 0);
  }

  float* O = out + (size_t)tb * TBC;
  const float* sbn = bnw + 3 * 512;
  const int rbase = rt * 128;
#pragma unroll
  for (int i = 0; i < 4; ++i) {
    int co0 = rbase + wrow * 64 + i * 16 + ((L >> 4) << 2);
#pragma unroll
    for (int j = 0; j < 4; ++j) {
      int n = n0 + wcol * 64 + j * 16 + (L & 15);
      if (n < N_) {
#pragma unroll
        for (int r = 0; r < 4; ++r) {
          int co = co0 + r;
          float y = acc[i][j][r] * 0.125f;
          O[(size_t)co * N_ + n] = __fadd_rn(__fmul_rn(y, sbn[co]), sbn[256 + co]);
        }
      }
    }
  }
}

// ---------------------------------------------------------------------------
extern "C" void kernel_launch(void* const* d_in, const int* in_sizes, int n_in,
                              void* d_out, int out_size, void* d_ws, size_t ws_size,
                              hipStream_t stream) {
  const float* x   = (const float*)d_in[0];
  const float* qw  = (const float*)d_in[1];
  const float* qbn = (const float*)d_in[2];
  const float* kw  = (const float*)d_in[3];
  const float* kbn = (const float*)d_in[4];
  const float* vw  = (const float*)d_in[5];
  const float* vbn = (const float*)d_in[6];
  const float* pw  = (const float*)d_in[7];
  const float* pbn = (const float*)d_in[8];
  float* out = (float*)d_out;

  uint8_t* ws = (uint8_t*)d_ws;
  float* bnw           = (float*)ws;                           // 8 KB
  unsigned short* wsp  = (unsigned short*)(ws + 8192);         // 1.57 MB
  unsigned short* xsb  = (unsigned short*)(ws + 1581056);      // 52.43 MB
  uint8_t* qsb         = ws + 54009856;                        // 26.21 MB u8 blocked q
  uint8_t* ksp         = ws + 80224256;                        // 25.69 MB
  uint8_t* vsp         = ws + 105914368;                       // 25.69 MB
  int* kvg             = (int*)(ws + 131604480);               // 1.05 MB
  unsigned short* osb  = xsb;   // alias: xsb dead after qkv

  prep_quant<<<2625, 256, 0, stream>>>(x, xsb, qbn, kbn, vbn, pbn,
                                       qw, kw, vw, pw, bnw, wsp, kvg);
  qkv_mfma_sw<<<4800, 256, 0, stream>>>(xsb, wsp, bnw, qsb, ksp, vsp);
  attn_kv<<<dim3(8, 32, PARTS), 256, 0, stream>>>(ksp, vsp, kvg);
  attn_o_mfma<<<800, 256, 0, stream>>>(qsb, kvg, osb);
  out_mfma_sw<<<1600, 256, 0, stream>>>(osb, wsp, bnw, out);
}